// Round 5
// baseline (705.951 us; speedup 1.0000x reference)
//
#include <hip/hip_runtime.h>
#include <math.h>

#define NB 2
#define NY 360
#define NX 720
#define NZ 32
#define NPTS (NB*NY*NX*NZ)     // 16,588,800
#define NCOL (NB*NY*NX)        // 518,400

__device__ __forceinline__ int i4(int b,int y,int x,int z){ return (((b*NY)+y)*NX+x)*NZ+z; }
__device__ __forceinline__ int i3(int b,int y,int x){ return ((b*NY)+y)*NX+x; }

#define F_RAD   6371000.0f
#define F_OMEGA 7.292e-5f
#define F_CP    1004.0f
#define F_DLAT  ((float)(M_PI/360.0))                 /* == dlon */
#define F_DYR   ((float)(M_PI/360.0*6371000.0))      /* dlat*RAD */
#define F_HPI   ((float)(M_PI/2.0))
#define TH      ((float)(2.0*M_PI/720.0))

// -------------------- kernel 1: div_h = du/dx + dv/dy --------------------
__global__ __launch_bounds__(256) void k_divh(const float* __restrict__ u,
                                              const float* __restrict__ v,
                                              float* __restrict__ divh) {
  int gid = blockIdx.x*256 + threadIdx.x;          // exact: 64800*256 = NPTS
  int z  = gid & 31;
  int x  = (gid >> 5) % NX;
  int by = gid / (NX*NZ);
  int y  = by % NY;
  int b  = by / NY;
  float lat = -F_HPI + (y+0.5f)*F_DLAT;
  float cl  = cosf(lat);
  float invdx = 0.5f/(F_DLAT*F_RAD*cl);
  int xp = (x==NX-1)?0:x+1, xm = (x==0)?NX-1:x-1;
  float dudx = (u[i4(b,y,xp,z)] - u[i4(b,y,xm,z)]) * invdx;
  float dvdy;
  if (y == 0)          dvdy = (v[i4(b,1,x,z)]    - v[i4(b,0,x,z)])    * (1.0f/F_DYR);
  else if (y == NY-1)  dvdy = (v[i4(b,NY-1,x,z)] - v[i4(b,NY-2,x,z)]) * (1.0f/F_DYR);
  else                 dvdy = (v[i4(b,y+1,x,z)]  - v[i4(b,y-1,x,z)])  * (0.5f/F_DYR);
  divh[gid] = dudx + dvdy;
}

// -------------------- kernel 2: all raw tendencies --------------------
__global__ __launch_bounds__(256) void k_tend(
    const float* __restrict__ u, const float* __restrict__ v,
    const float* __restrict__ T, const float* __restrict__ ps,
    const float* __restrict__ Rp, const float* __restrict__ divh,
    float* __restrict__ du, float* __restrict__ dv,
    float* __restrict__ dT, float* __restrict__ dps) {
  const int tid = threadIdx.x;
  const int z   = tid & 31;
  const int col = blockIdx.x*8 + (tid>>5);         // exact: 64800*8 = NCOL
  const int x = col % NX;
  const int y = (col / NX) % NY;
  const int b = col / (NX*NY);
  const float R = Rp[0];

  const int xp = (x==NX-1)?0:x+1, xm = (x==0)?NX-1:x-1;
  const int ycm = (y>0)? y-1 : 0;
  const int ycp = (y<NY-1)? y+1 : NY-1;
  const bool y0 = (y==0), yN = (y==NY-1);

  const float lat  = -F_HPI + (y+0.5f)*F_DLAT;
  const float cl   = cosf(lat);
  const float fcor = 2.0f*F_OMEGA*sinf(lat);
  const float sx     = F_DLAT*F_RAD*cl;
  const float invdx  = 0.5f/sx;
  const float inv2dy = 0.5f/F_DYR;
  const float inv1dy = 1.0f/F_DYR;
  const float invsx2 = 1.0f/(sx*sx);
  const float invsy2 = 1.0f/(F_DYR*F_DYR);
  const float bk  = (z + 0.5f)/32.0f;
  const float dsv = 1.0f/32.0f;

  const int ic  = i4(b,y,x,z),   ixp = i4(b,y,xp,z), ixm = i4(b,y,xm,z);
  const int iyp = i4(b,ycp,x,z), iym = i4(b,ycm,x,z);

  const float uc=u[ic], uxp=u[ixp], uxm=u[ixm], uyp=u[iyp], uym=u[iym];
  const float vc=v[ic], vxp=v[ixp], vxm=v[ixm], vyp=v[iyp], vym=v[iym];
  const float Tc=T[ic], Txp=T[ixp], Txm=T[ixm], Typ=T[iyp], Tym=T[iym];
  const float Dc=divh[ic], Dxp=divh[ixp], Dxm=divh[ixm], Dyp=divh[iyp], Dym=divh[iym];
  const float psc=ps[i3(b,y,x)],   psxp=ps[i3(b,y,xp)], psxm=ps[i3(b,y,xm)];
  const float psyp=ps[i3(b,ycp,x)], psym=ps[i3(b,ycm,x)];

  auto dfy = [&](float fc_, float fyp_, float fym_) -> float {
    if (y0) return (fyp_ - fc_) * inv1dy;
    if (yN) return (fc_ - fym_) * inv1dy;
    return (fyp_ - fym_) * inv2dy;
  };
  auto lap = [&](float fc_, float fxp_, float fxm_, float fyp_, float fym_) -> float {
    float d2x = (fxp_ + fxm_ - 2.0f*fc_) * invsx2;
    float d2y = (y0||yN) ? 0.0f : (fyp_ + fym_ - 2.0f*fc_) * invsy2;
    return d2x + d2y;
  };
  auto sufscan = [&](float vv) -> float {   // vv[z] = sum_{j>=z}
    #pragma unroll
    for (int d=1; d<32; d<<=1) { float t = __shfl_down(vv, d, 32); if (z+d<32) vv += t; }
    return vv;
  };
  auto prescan = [&](float vv) -> float {   // vv[z] = sum_{j<=z}
    #pragma unroll
    for (int d=1; d<32; d<<=1) { float t = __shfl_up(vv, d, 32); if (z>=d) vv += t; }
    return vv;
  };
  auto vg = [&](float fc_) -> float {       // d/dsigma
    float fzp = __shfl_down(fc_,1,32), fzm = __shfl_up(fc_,1,32);
    if (z==0)  return (fzp - fc_) * 32.0f;
    if (z==31) return (fc_ - fzm) * 32.0f;
    return (fzp - fzm) * 16.0f;
  };

  const float rz = dsv / bk;
  const float phic  = sufscan(R*Tc*rz);
  const float phixp = sufscan(R*Txp*rz);
  const float phixm = sufscan(R*Txm*rz);
  const float phiyp = sufscan(R*Typ*rz);
  const float phiym = sufscan(R*Tym*rz);

  const float dudx = (uxp-uxm)*invdx, dvdx = (vxp-vxm)*invdx, dTdx = (Txp-Txm)*invdx;
  const float dphidx = (phixp-phixm)*invdx;
  const float dudy = dfy(uc,uyp,uym), dvdy_ = dfy(vc,vyp,vym), dTdy = dfy(Tc,Typ,Tym);
  const float dphidy = dfy(phic,phiyp,phiym);
  const float dpsdx = (psxp-psxm)*invdx, dpsdy = dfy(psc,psyp,psym);
  const float gdivx = (Dxp-Dxm)*invdx,  gdivy = dfy(Dc,Dyp,Dym);

  const float mass = Dc*psc + uc*dpsdx + vc*dpsdy;
  float Ipre = prescan(mass) * dsv;
  const float Itot = __shfl(Ipre, 31, 32);
  const float sigd = (bk*Itot - Ipre) / (psc + 1e-8f);

  const float vgu = vg(uc), vgv = vg(vc), vgT = vg(Tc);

  const float pfac = R*Tc*bk/(bk*psc + 1e-8f);
  const float pgfu = -dphidx - pfac*dpsdx;
  const float pgfv = -dphidy - pfac*dpsdy;
  const float cf2  = fmaxf(cl*cl, 0.01f);
  const float nudiv = 500000.0f*cf2, nuh = 100000.0f*cf2;
  const float lapu = lap(uc,uxp,uxm,uyp,uym);
  const float lapv = lap(vc,vxp,vxm,vyp,vym);
  const float lapT = lap(Tc,Txp,Txm,Typ,Tym);
  const float adiab = R*Tc/(bk*psc*F_CP + 1e-8f) * (sigd*psc);

  float dut = -(uc*dudx + vc*dudy)  - sigd*vgu + fcor*vc + pgfu + nuh*lapu - 1e-5f*uc + nudiv*gdivx;
  float dvt = -(uc*dvdx + vc*dvdy_) - sigd*vgv - fcor*uc + pgfv + nuh*lapv - 1e-5f*vc + nudiv*gdivy;
  float dTt = -(uc*dTdx + vc*dTdy)  - sigd*vgT + adiab + nuh*lapT;

  du[ic] = dut; dv[ic] = dvt; dT[ic] = dTt;
  if (z == 0) dps[i3(b,y,x)] = -Itot;
}

// -------------------- kernel 3: zero dqdt --------------------
__global__ __launch_bounds__(256) void k_zero(float4* __restrict__ p) {
  p[blockIdx.x*256 + threadIdx.x] = make_float4(0.f,0.f,0.f,0.f);
}

// -------------------- polar filter helpers --------------------
__device__ __forceinline__ void filter_band(int y, int& k0, int& k1, bool& keepmode) {
  float lat = -F_HPI + (y+0.5f)*F_DLAT;
  float cut = fmaxf(360.0f*cosf(lat), 1.0f);
  int M = (int)floorf(cut);
  keepmode = (M <= 179);
  k0 = keepmode ? 0 : (M+1);
  k1 = keepmode ? M : 360;
}

// -------------------- kernel 4: folded-DFT polar filter, 3 fields ---------
// Quarter-fold: x = x' + 180*j. Analysis over 180 x' with folded inputs
// (S0,S2 real for k even; A,B complex for k odd). Padded LDS rows (odd
// multiples of 16B: 12/28/20 floats) make all b128 accesses hit the minimum
// 8 bank rounds (stride-32B rows were 16-way conflicts — Round-4 counters).
// Analysis thread = (k-slot, x-chunk): 8 z per thread (rotation amortized
// over 16 FMAs, was 4), partials reduced via shfl_xor over the 4 chunk lanes.
__global__ __launch_bounds__(384) void k_filter4b(
    float* __restrict__ du, float* __restrict__ dv, float* __restrict__ dT) {
  __shared__ float S0f[180*12];      // [x][z0..7 | pad4], stride 48B (odd 16B units)
  __shared__ float S2f[180*12];
  __shared__ float ABf[180*28];      // [x][A0,B0,..,A7,B7 | pad12], stride 112B
  __shared__ float SDf[180*20];      // [k][c0,s0,..,c7,s7 | pad4], stride 80B

  const int tid  = threadIdx.x;
  const int zq   = blockIdx.x & 3;
  const int rest = blockIdx.x >> 2;
  const int by   = rest % (NB*NY);
  const int fld  = rest / (NB*NY);
  const int y = by % NY, b = by / NY;
  float* fptr = (fld==0)? du : (fld==1)? dv : dT;
  const float clipv = (fld==2)? 0.01f : 0.02f;
  float* base = fptr + ((size_t)(b*NY+y)*NX)*NZ + zq*8;

  int k0, k1; bool keep;
  filter_band(y, k0, k1, keep);

  // ---- load + fold ----
  if (tid < 360) {
    const int x  = tid % 180;
    const int zh = tid / 180;                       // 0/1 -> z offset 4*zh
    const float4 q0 = *(const float4*)(base + (size_t)(x      )*NZ + zh*4);
    const float4 q1 = *(const float4*)(base + (size_t)(x + 180)*NZ + zh*4);
    const float4 q2 = *(const float4*)(base + (size_t)(x + 360)*NZ + zh*4);
    const float4 q3 = *(const float4*)(base + (size_t)(x + 540)*NZ + zh*4);
    float4 s0v, s2v, av, bv;
    s0v.x=q0.x+q1.x+q2.x+q3.x; s2v.x=q0.x-q1.x+q2.x-q3.x; av.x=q0.x-q2.x; bv.x=q1.x-q3.x;
    s0v.y=q0.y+q1.y+q2.y+q3.y; s2v.y=q0.y-q1.y+q2.y-q3.y; av.y=q0.y-q2.y; bv.y=q1.y-q3.y;
    s0v.z=q0.z+q1.z+q2.z+q3.z; s2v.z=q0.z-q1.z+q2.z-q3.z; av.z=q0.z-q2.z; bv.z=q1.z-q3.z;
    s0v.w=q0.w+q1.w+q2.w+q3.w; s2v.w=q0.w-q1.w+q2.w-q3.w; av.w=q0.w-q2.w; bv.w=q1.w-q3.w;
    *(float4*)&S0f[x*12 + zh*4] = s0v;
    *(float4*)&S2f[x*12 + zh*4] = s2v;
    *(float4*)&ABf[x*28 + zh*8 + 0] = make_float4(av.x, bv.x, av.y, bv.y);
    *(float4*)&ABf[x*28 + zh*8 + 4] = make_float4(av.z, bv.z, av.w, bv.w);
  }
  __syncthreads();

  // ---- analysis ----
  {
    const int xc = tid & 3;            // x-chunk 0..3 (45 x each)
    const int ks = tid >> 2;           // 0..95; waves 0-2 even-k, 3-5 odd-k
    const bool isodd = (ks >= 48);
    const int m = isodd ? ks - 48 : ks;
    const int kfirst = k0 + ((k0 & 1) ^ (isodd ? 1 : 0));
    const int ka = kfirst + 2*m;
    const int kb = ka + 96;
    const bool va = (ka <= k1);
    const bool vb = (kb <= k1);

    float cA[8], sA[8], cB[8], sB[8];
    #pragma unroll
    for (int z=0;z<8;++z){ cA[z]=0.f; sA[z]=0.f; cB[z]=0.f; sB[z]=0.f; }

    if (va) {
      const int x0 = xc*45, x1e = x0+45;
      float c1,s1,dc1,ds1, c2=1.f,s2=0.f,dc2=1.f,ds2=0.f;
      sincosf((float)((ka*x0)%720)*TH, &s1, &c1);
      sincosf((float)ka*TH, &ds1, &dc1);
      if (vb) {
        sincosf((float)((kb*x0)%720)*TH, &s2, &c2);
        sincosf((float)kb*TH, &ds2, &dc2);
      }
      if (!isodd) {
        const float* Sp = ((ka & 3) == 0) ? S0f : S2f;
        for (int x = x0; x < x1e; ++x) {
          const float4 a  = *(const float4*)&Sp[x*12];
          const float4 b4 = *(const float4*)&Sp[x*12+4];
          const float v[8] = {a.x,a.y,a.z,a.w,b4.x,b4.y,b4.z,b4.w};
          #pragma unroll
          for (int z=0;z<8;++z){ cA[z]=fmaf(v[z],c1,cA[z]); sA[z]=fmaf(v[z],s1,sA[z]); }
          { float n=fmaf(c1,dc1,-s1*ds1); s1=fmaf(s1,dc1,c1*ds1); c1=n; }
          if (vb) {
            #pragma unroll
            for (int z=0;z<8;++z){ cB[z]=fmaf(v[z],c2,cB[z]); sB[z]=fmaf(v[z],s2,sB[z]); }
            float n=fmaf(c2,dc2,-s2*ds2); s2=fmaf(s2,dc2,c2*ds2); c2=n;
          }
        }
      } else {
        const float sg = ((ka & 3) == 1) ? 1.0f : -1.0f;   // kb same residue (96%4==0)
        for (int x = x0; x < x1e; ++x) {
          const float4 p0 = *(const float4*)&ABf[x*28+0];
          const float4 p1 = *(const float4*)&ABf[x*28+4];
          const float4 p2 = *(const float4*)&ABf[x*28+8];
          const float4 p3 = *(const float4*)&ABf[x*28+12];
          const float Av[8] = {p0.x,p0.z,p1.x,p1.z,p2.x,p2.z,p3.x,p3.z};
          const float Bv[8] = {p0.y,p0.w,p1.y,p1.w,p2.y,p2.w,p3.y,p3.w};
          #pragma unroll
          for (int z=0;z<8;++z){
            const float t = sg*Bv[z];
            cA[z] = fmaf(Av[z],c1, fmaf(t,-s1, cA[z]));
            sA[z] = fmaf(Av[z],s1, fmaf(t, c1, sA[z]));
          }
          { float n=fmaf(c1,dc1,-s1*ds1); s1=fmaf(s1,dc1,c1*ds1); c1=n; }
          if (vb) {
            #pragma unroll
            for (int z=0;z<8;++z){
              const float t = sg*Bv[z];
              cB[z] = fmaf(Av[z],c2, fmaf(t,-s2, cB[z]));
              sB[z] = fmaf(Av[z],s2, fmaf(t, c2, sB[z]));
            }
            float n=fmaf(c2,dc2,-s2*ds2); s2=fmaf(s2,dc2,c2*ds2); c2=n;
          }
        }
      }
    }
    // butterfly-reduce partials over the 4 x-chunk lanes (va/vb uniform in group)
    #pragma unroll
    for (int z=0;z<8;++z){
      cA[z] += __shfl_xor(cA[z],1); cA[z] += __shfl_xor(cA[z],2);
      sA[z] += __shfl_xor(sA[z],1); sA[z] += __shfl_xor(sA[z],2);
      cB[z] += __shfl_xor(cB[z],1); cB[z] += __shfl_xor(cB[z],2);
      sB[z] += __shfl_xor(sB[z],1); sB[z] += __shfl_xor(sB[z],2);
    }
    if (xc == 0 && va) {
      const float w = (ka==0||ka==360)?1.f:2.f; const int r = ka-k0;
      *(float4*)&SDf[r*20+0] = make_float4(w*cA[0],w*sA[0],w*cA[1],w*sA[1]);
      *(float4*)&SDf[r*20+4] = make_float4(w*cA[2],w*sA[2],w*cA[3],w*sA[3]);
    } else if (xc == 1 && va) {
      const float w = (ka==0||ka==360)?1.f:2.f; const int r = ka-k0;
      *(float4*)&SDf[r*20+8]  = make_float4(w*cA[4],w*sA[4],w*cA[5],w*sA[5]);
      *(float4*)&SDf[r*20+12] = make_float4(w*cA[6],w*sA[6],w*cA[7],w*sA[7]);
    } else if (xc == 2 && vb) {
      const float w = (kb==0||kb==360)?1.f:2.f; const int r = kb-k0;
      *(float4*)&SDf[r*20+0] = make_float4(w*cB[0],w*sB[0],w*cB[1],w*sB[1]);
      *(float4*)&SDf[r*20+4] = make_float4(w*cB[2],w*sB[2],w*cB[3],w*sB[3]);
    } else if (xc == 3 && vb) {
      const float w = (kb==0||kb==360)?1.f:2.f; const int r = kb-k0;
      *(float4*)&SDf[r*20+8]  = make_float4(w*cB[4],w*sB[4],w*cB[5],w*sB[5]);
      *(float4*)&SDf[r*20+12] = make_float4(w*cB[6],w*sB[6],w*cB[7],w*sB[7]);
    }
  }
  __syncthreads();

  // ---- synthesis: thread = (x' 0..179, z-half 0..1), 4 z each ----
  if (tid < 360) {
    const int x  = tid % 180;
    const int zh = tid / 180;
    float HreE[2][4]; float Hro[2][4]; float Hio[2][4];
    #pragma unroll
    for (int i = 0; i < 2; ++i)
      #pragma unroll
      for (int j = 0; j < 4; ++j) { HreE[i][j]=0.f; Hro[i][j]=0.f; Hio[i][j]=0.f; }

    const int m4 = (4*x) % 720;
    float dstep_s, dstep_c; sincosf((float)m4 * TH, &dstep_s, &dstep_c);

    // even residues r=0,2: only Re needed
    #pragma unroll
    for (int ri = 0; ri < 2; ++ri) {
      const int r = ri*2;
      const int kst = k0 + ((r - (k0 & 3) + 4) & 3);
      if (kst > k1) continue;
      int mm = (kst * x) % 720;
      float sv, cv; sincosf((float)mm * TH, &sv, &cv);
      for (int k = kst; k <= k1; k += 4) {
        const float4 d01 = *(const float4*)&SDf[(k - k0)*20 + zh*8 + 0];
        const float4 d23 = *(const float4*)&SDf[(k - k0)*20 + zh*8 + 4];
        HreE[ri][0] = fmaf(d01.x, cv, fmaf(d01.y, sv, HreE[ri][0]));
        HreE[ri][1] = fmaf(d01.z, cv, fmaf(d01.w, sv, HreE[ri][1]));
        HreE[ri][2] = fmaf(d23.x, cv, fmaf(d23.y, sv, HreE[ri][2]));
        HreE[ri][3] = fmaf(d23.z, cv, fmaf(d23.w, sv, HreE[ri][3]));
        float nc = fmaf(cv, dstep_c, -sv*dstep_s);   // forward rotation +4x*theta
        float ns = fmaf(sv, dstep_c,  cv*dstep_s);
        cv = nc; sv = ns;
      }
    }
    // odd residues r=1,3: Re and Im
    #pragma unroll
    for (int ri = 0; ri < 2; ++ri) {
      const int r = ri*2 + 1;
      const int kst = k0 + ((r - (k0 & 3) + 4) & 3);
      if (kst > k1) continue;
      int mm = (kst * x) % 720;
      float sv, cv; sincosf((float)mm * TH, &sv, &cv);
      for (int k = kst; k <= k1; k += 4) {
        const float4 d01 = *(const float4*)&SDf[(k - k0)*20 + zh*8 + 0];
        const float4 d23 = *(const float4*)&SDf[(k - k0)*20 + zh*8 + 4];
        Hro[ri][0] = fmaf(d01.x, cv, fmaf(d01.y, sv, Hro[ri][0]));
        Hio[ri][0] = fmaf(d01.y, cv, fmaf(-d01.x, sv, Hio[ri][0]));
        Hro[ri][1] = fmaf(d01.z, cv, fmaf(d01.w, sv, Hro[ri][1]));
        Hio[ri][1] = fmaf(d01.w, cv, fmaf(-d01.z, sv, Hio[ri][1]));
        Hro[ri][2] = fmaf(d23.x, cv, fmaf(d23.y, sv, Hro[ri][2]));
        Hio[ri][2] = fmaf(d23.y, cv, fmaf(-d23.x, sv, Hio[ri][2]));
        Hro[ri][3] = fmaf(d23.z, cv, fmaf(d23.w, sv, Hro[ri][3]));
        Hio[ri][3] = fmaf(d23.w, cv, fmaf(-d23.z, sv, Hio[ri][3]));
        float nc = fmaf(cv, dstep_c, -sv*dstep_s);   // forward rotation +4x*theta
        float ns = fmaf(sv, dstep_c,  cv*dstep_s);
        cv = nc; sv = ns;
      }
    }

    const float inv = 1.0f/720.0f;
    float o[4][4];
    float4 s0v, s2v, ab01, ab23;
    if (!keep) {
      s0v  = *(const float4*)&S0f[x*12 + zh*4];
      s2v  = *(const float4*)&S2f[x*12 + zh*4];
      ab01 = *(const float4*)&ABf[x*28 + zh*8 + 0];
      ab23 = *(const float4*)&ABf[x*28 + zh*8 + 4];
    }
    #pragma unroll
    for (int j = 0; j < 4; ++j) {
      const float h0  = HreE[0][j], h2 = HreE[1][j];
      const float h1r = Hro[0][j],  h1i = Hio[0][j];
      const float h3r = Hro[1][j],  h3i = Hio[1][j];
      float l0 = (h0 + h1r + h2 + h3r) * inv;
      float l1 = (h0 + h1i - h2 - h3i) * inv;
      float l2 = (h0 - h1r + h2 - h3r) * inv;
      float l3 = (h0 - h1i - h2 + h3i) * inv;
      if (!keep) {
        const float s0j = (j==0)?s0v.x:(j==1)?s0v.y:(j==2)?s0v.z:s0v.w;
        const float s2j = (j==0)?s2v.x:(j==1)?s2v.y:(j==2)?s2v.z:s2v.w;
        const float aj  = (j==0)?ab01.x:(j==1)?ab01.z:(j==2)?ab23.x:ab23.z;
        const float bj  = (j==0)?ab01.y:(j==1)?ab01.w:(j==2)?ab23.y:ab23.w;
        const float sp = 0.25f*(s0j + s2j), sm = 0.25f*(s0j - s2j);
        const float q0v = sp + 0.5f*aj, q2v = sp - 0.5f*aj;
        const float q1v = sm + 0.5f*bj, q3v = sm - 0.5f*bj;
        l0 = q0v - l0; l1 = q1v - l1; l2 = q2v - l2; l3 = q3v - l3;
      }
      o[0][j] = fminf(fmaxf(l0, -clipv), clipv);
      o[1][j] = fminf(fmaxf(l1, -clipv), clipv);
      o[2][j] = fminf(fmaxf(l2, -clipv), clipv);
      o[3][j] = fminf(fmaxf(l3, -clipv), clipv);
    }
    #pragma unroll
    for (int j = 0; j < 4; ++j) {
      *(float4*)(base + (size_t)(x + 180*j)*NZ + zh*4) =
          make_float4(o[j][0], o[j][1], o[j][2], o[j][3]);
    }
  }
}

// -------------------- kernel 5: polar filter for dpsdt (3D) ----------------
__global__ __launch_bounds__(384) void k_filter_ps(float* __restrict__ dps) {
  __shared__ float  f[NX];
  __shared__ float2 tw[NX];
  __shared__ float  sc[184], ss[184];
  const int tid = threadIdx.x;
  const int row = blockIdx.x;       // 0..719 = b*360+y
  const int y = row % NY;
  float* base = dps + (size_t)row*NX;
  for (int t = tid; t < NX; t += 384) {
    float a = (float)t * (float)(2.0*M_PI/720.0);
    float sv, cv; sincosf(a, &sv, &cv);
    tw[t] = make_float2(cv, sv);
    f[t] = base[t];
  }
  int k0, k1; bool keepmode;
  filter_band(y, k0, k1, keepmode);
  const int nk = k1 - k0 + 1;
  __syncthreads();

  if (tid < nk) {
    const int k = k0 + tid;
    float ac=0.f, as=0.f; int idx=0;
    for (int xx=0; xx<NX; ++xx) {
      const float fv = f[xx];
      const float2 t2 = tw[idx];
      ac = fmaf(fv, t2.x, ac); as = fmaf(fv, t2.y, as);
      idx += k; if (idx >= NX) idx -= NX;
    }
    sc[tid]=ac; ss[tid]=as;
  }
  __syncthreads();

  if (tid < 360) {
    const int x0 = tid, x1 = tid + 360;
    const int t0 = (x0 * k0) % NX;
    const int t1 = (x1 * k0) % NX;
    float c0 = tw[t0].x, s0 = tw[t0].y;
    float c1 = tw[t1].x, s1 = tw[t1].y;
    const float dc0 = tw[x0].x, dn0 = tw[x0].y;
    const float dc1 = tw[x1].x, dn1 = tw[x1].y;
    float a0 = 0.f, a1 = 0.f;
    for (int kk = 0; kk < nk; ++kk) {
      const int k = k0 + kk;
      const float w = (k==0 || k==360) ? 1.0f : 2.0f;
      a0 = fmaf(sc[kk], w*c0, fmaf(ss[kk], w*s0, a0));
      a1 = fmaf(sc[kk], w*c1, fmaf(ss[kk], w*s1, a1));
      float n0 = c0*dc0 - s0*dn0; s0 = c0*dn0 + s0*dc0; c0 = n0;
      float n1 = c1*dc1 - s1*dn1; s1 = c1*dn1 + s1*dc1; c1 = n1;
    }
    const float inv = 1.0f/720.0f;
    float o0 = keepmode ? a0*inv : f[x0] - a0*inv;
    float o1 = keepmode ? a1*inv : f[x1] - a1*inv;
    o0 = fminf(fmaxf(o0, -0.5f), 0.5f);
    o1 = fminf(fmaxf(o1, -0.5f), 0.5f);
    base[x0] = o0;
    base[x1] = o1;
  }
}

// -------------------- host --------------------
extern "C" void kernel_launch(void* const* d_in, const int* in_sizes, int n_in,
                              void* d_out, int out_size, void* d_ws, size_t ws_size,
                              hipStream_t stream) {
  (void)in_sizes; (void)n_in; (void)d_ws; (void)ws_size; (void)out_size;
  const float* u  = (const float*)d_in[0];
  const float* v  = (const float*)d_in[1];
  const float* T  = (const float*)d_in[2];
  const float* ps = (const float*)d_in[4];
  const float* Rp = (const float*)d_in[6];

  float* out = (float*)d_out;
  float* du  = out;
  float* dv  = out + (size_t)NPTS;
  float* dT  = out + (size_t)2*NPTS;
  float* dq  = out + (size_t)3*NPTS;   // staged as div_h scratch, zeroed below
  float* dps = out + (size_t)4*NPTS;

  k_divh<<<NPTS/256, 256, 0, stream>>>(u, v, dq);
  k_tend<<<NCOL/8,   256, 0, stream>>>(u, v, T, ps, Rp, dq, du, dv, dT, dps);
  k_zero<<<NPTS/(256*4), 256, 0, stream>>>((float4*)dq);
  k_filter4b<<<3*NB*NY*4, 384, 0, stream>>>(du, dv, dT);
  k_filter_ps<<<NB*NY, 384, 0, stream>>>(dps);
}

// Round 6
// 694.734 us; speedup vs baseline: 1.0161x; 1.0161x over previous
//
#include <hip/hip_runtime.h>
#include <math.h>

#define NB 2
#define NY 360
#define NX 720
#define NZ 32
#define NPTS (NB*NY*NX*NZ)     // 16,588,800
#define NCOL (NB*NY*NX)        // 518,400

__device__ __forceinline__ int i4(int b,int y,int x,int z){ return (((b*NY)+y)*NX+x)*NZ+z; }
__device__ __forceinline__ int i3(int b,int y,int x){ return ((b*NY)+y)*NX+x; }

#define F_RAD   6371000.0f
#define F_OMEGA 7.292e-5f
#define F_CP    1004.0f
#define F_DLAT  ((float)(M_PI/360.0))                 /* == dlon */
#define F_DYR   ((float)(M_PI/360.0*6371000.0))      /* dlat*RAD */
#define F_HPI   ((float)(M_PI/2.0))
#define TH      ((float)(2.0*M_PI/720.0))

// -------------------- kernel 1: all raw tendencies (div_h fused) ----------
// div_h recomputed inline at the 5 stencil points (bitwise-same formula as
// the old k_divh) — saves the 66MB divh write + re-read and two dispatches.
__global__ __launch_bounds__(256) void k_tend(
    const float* __restrict__ u, const float* __restrict__ v,
    const float* __restrict__ T, const float* __restrict__ ps,
    const float* __restrict__ Rp,
    float* __restrict__ du, float* __restrict__ dv,
    float* __restrict__ dT, float* __restrict__ dq,
    float* __restrict__ dps) {
  const int tid = threadIdx.x;
  const int z   = tid & 31;
  const int col = blockIdx.x*8 + (tid>>5);         // exact: 64800*8 = NCOL
  const int x = col % NX;
  const int y = (col / NX) % NY;
  const int b = col / (NX*NY);
  const float R = Rp[0];

  const int xp = (x==NX-1)?0:x+1, xm = (x==0)?NX-1:x-1;
  const int ycm = (y>0)? y-1 : 0;
  const int ycp = (y<NY-1)? y+1 : NY-1;
  const bool y0 = (y==0), yN = (y==NY-1);

  const float lat  = -F_HPI + (y+0.5f)*F_DLAT;
  const float cl   = cosf(lat);
  const float fcor = 2.0f*F_OMEGA*sinf(lat);
  const float sx     = F_DLAT*F_RAD*cl;
  const float invdx  = 0.5f/sx;
  const float inv2dy = 0.5f/F_DYR;
  const float inv1dy = 1.0f/F_DYR;
  const float invsx2 = 1.0f/(sx*sx);
  const float invsy2 = 1.0f/(F_DYR*F_DYR);
  const float bk  = (z + 0.5f)/32.0f;
  const float dsv = 1.0f/32.0f;

  const int ic  = i4(b,y,x,z),   ixp = i4(b,y,xp,z), ixm = i4(b,y,xm,z);
  const int iyp = i4(b,ycp,x,z), iym = i4(b,ycm,x,z);

  const float uc=u[ic], uxp=u[ixp], uxm=u[ixm], uyp=u[iyp], uym=u[iym];
  const float vc=v[ic], vxp=v[ixp], vxm=v[ixm], vyp=v[iyp], vym=v[iym];
  const float Tc=T[ic], Txp=T[ixp], Txm=T[ixm], Typ=T[iyp], Tym=T[iym];
  const float psc=ps[i3(b,y,x)],   psxp=ps[i3(b,y,xp)], psxm=ps[i3(b,y,xm)];
  const float psyp=ps[i3(b,ycp,x)], psym=ps[i3(b,ycm,x)];

  // inline div_h = du/dx + dv/dy at arbitrary (yy, xx) — formula identical
  // to the old k_divh (same fp ordering, same boundary handling).
  auto divAt = [&](int yy, int xx) -> float {
    const int xxp = (xx==NX-1)?0:xx+1, xxm = (xx==0)?NX-1:xx-1;
    const float cly = cosf(-F_HPI + (yy+0.5f)*F_DLAT);
    const float ddx = (u[i4(b,yy,xxp,z)] - u[i4(b,yy,xxm,z)]) * (0.5f/(F_DLAT*F_RAD*cly));
    float ddy;
    if (yy == 0)          ddy = (v[i4(b,1,xx,z)]    - v[i4(b,0,xx,z)])    * inv1dy;
    else if (yy == NY-1)  ddy = (v[i4(b,NY-1,xx,z)] - v[i4(b,NY-2,xx,z)]) * inv1dy;
    else                  ddy = (v[i4(b,yy+1,xx,z)] - v[i4(b,yy-1,xx,z)]) * inv2dy;
    return ddx + ddy;
  };
  const float Dc  = divAt(y,x);
  const float Dxp = divAt(y,xp), Dxm = divAt(y,xm);
  const float Dyp = divAt(ycp,x), Dym = divAt(ycm,x);

  auto dfy = [&](float fc_, float fyp_, float fym_) -> float {
    if (y0) return (fyp_ - fc_) * inv1dy;
    if (yN) return (fc_ - fym_) * inv1dy;
    return (fyp_ - fym_) * inv2dy;
  };
  auto lap = [&](float fc_, float fxp_, float fxm_, float fyp_, float fym_) -> float {
    float d2x = (fxp_ + fxm_ - 2.0f*fc_) * invsx2;
    float d2y = (y0||yN) ? 0.0f : (fyp_ + fym_ - 2.0f*fc_) * invsy2;
    return d2x + d2y;
  };
  auto sufscan = [&](float vv) -> float {   // vv[z] = sum_{j>=z}
    #pragma unroll
    for (int d=1; d<32; d<<=1) { float t = __shfl_down(vv, d, 32); if (z+d<32) vv += t; }
    return vv;
  };
  auto prescan = [&](float vv) -> float {   // vv[z] = sum_{j<=z}
    #pragma unroll
    for (int d=1; d<32; d<<=1) { float t = __shfl_up(vv, d, 32); if (z>=d) vv += t; }
    return vv;
  };
  auto vg = [&](float fc_) -> float {       // d/dsigma
    float fzp = __shfl_down(fc_,1,32), fzm = __shfl_up(fc_,1,32);
    if (z==0)  return (fzp - fc_) * 32.0f;
    if (z==31) return (fc_ - fzm) * 32.0f;
    return (fzp - fzm) * 16.0f;
  };

  const float rz = dsv / bk;
  const float phic  = sufscan(R*Tc*rz);
  const float phixp = sufscan(R*Txp*rz);
  const float phixm = sufscan(R*Txm*rz);
  const float phiyp = sufscan(R*Typ*rz);
  const float phiym = sufscan(R*Tym*rz);

  const float dudx = (uxp-uxm)*invdx, dvdx = (vxp-vxm)*invdx, dTdx = (Txp-Txm)*invdx;
  const float dphidx = (phixp-phixm)*invdx;
  const float dudy = dfy(uc,uyp,uym), dvdy_ = dfy(vc,vyp,vym), dTdy = dfy(Tc,Typ,Tym);
  const float dphidy = dfy(phic,phiyp,phiym);
  const float dpsdx = (psxp-psxm)*invdx, dpsdy = dfy(psc,psyp,psym);
  const float gdivx = (Dxp-Dxm)*invdx,  gdivy = dfy(Dc,Dyp,Dym);

  const float mass = Dc*psc + uc*dpsdx + vc*dpsdy;
  float Ipre = prescan(mass) * dsv;
  const float Itot = __shfl(Ipre, 31, 32);
  const float sigd = (bk*Itot - Ipre) / (psc + 1e-8f);

  const float vgu = vg(uc), vgv = vg(vc), vgT = vg(Tc);

  const float pfac = R*Tc*bk/(bk*psc + 1e-8f);
  const float pgfu = -dphidx - pfac*dpsdx;
  const float pgfv = -dphidy - pfac*dpsdy;
  const float cf2  = fmaxf(cl*cl, 0.01f);
  const float nudiv = 500000.0f*cf2, nuh = 100000.0f*cf2;
  const float lapu = lap(uc,uxp,uxm,uyp,uym);
  const float lapv = lap(vc,vxp,vxm,vyp,vym);
  const float lapT = lap(Tc,Txp,Txm,Typ,Tym);
  const float adiab = R*Tc/(bk*psc*F_CP + 1e-8f) * (sigd*psc);

  float dut = -(uc*dudx + vc*dudy)  - sigd*vgu + fcor*vc + pgfu + nuh*lapu - 1e-5f*uc + nudiv*gdivx;
  float dvt = -(uc*dvdx + vc*dvdy_) - sigd*vgv - fcor*uc + pgfv + nuh*lapv - 1e-5f*vc + nudiv*gdivy;
  float dTt = -(uc*dTdx + vc*dTdy)  - sigd*vgT + adiab + nuh*lapT;

  du[ic] = dut; dv[ic] = dvt; dT[ic] = dTt; dq[ic] = 0.0f;
  if (z == 0) dps[i3(b,y,x)] = -Itot;
}

// -------------------- polar filter helpers --------------------
__device__ __forceinline__ void filter_band(int y, int& k0, int& k1, bool& keepmode) {
  float lat = -F_HPI + (y+0.5f)*F_DLAT;
  float cut = fmaxf(360.0f*cosf(lat), 1.0f);
  int M = (int)floorf(cut);
  keepmode = (M <= 179);
  k0 = keepmode ? 0 : (M+1);
  k1 = keepmode ? M : 360;
}

// -------------------- kernel 2: folded-DFT polar filter, 3 fields ---------
// R4 base (unpadded LDS, 34.5KB -> 4 blocks/CU) + analysis remap: thread =
// (kv 0..191, zh 0..1), ONE k x 4 z per thread, single rotation chain
// (R4 ran two chains per slot -> ~23% fewer analysis instrs). Parity-split
// kv keeps branches wave-uniform. XCD-chunked blockIdx swizzle puts the 4
// zq-sibling blocks (sharing cache lines) on one XCD.
#define FKMAX 180
__global__ __launch_bounds__(384) void k_filter4b(
    float* __restrict__ du, float* __restrict__ dv, float* __restrict__ dT) {
  __shared__ float S0[180][8];
  __shared__ float S2[180][8];
  __shared__ float AB[180][8][2];     // interleaved A,B
  __shared__ float SD[FKMAX][8][2];   // w*(c_k, s_k) per band index, per z

  const int tid  = threadIdx.x;
  // bijective XCD-chunk swizzle: 8640 = 8 * 1080
  const int bid  = (blockIdx.x & 7) * 1080 + (blockIdx.x >> 3);
  const int zq   = bid & 3;
  const int rest = bid >> 2;
  const int by   = rest % (NB*NY);
  const int fld  = rest / (NB*NY);
  const int y = by % NY, b = by / NY;
  float* fptr = (fld==0)? du : (fld==1)? dv : dT;
  const float clipv = (fld==2)? 0.01f : 0.02f;
  float* base = fptr + ((size_t)(b*NY+y)*NX)*NZ + zq*8;

  int k0, k1; bool keep;
  filter_band(y, k0, k1, keep);

  // ---- load + fold ----
  if (tid < 360) {
    const int x  = tid % 180;
    const int zh = tid / 180;                       // 0/1 -> z offset 4*zh
    const float4 q0 = *(const float4*)(base + (size_t)(x      )*NZ + zh*4);
    const float4 q1 = *(const float4*)(base + (size_t)(x + 180)*NZ + zh*4);
    const float4 q2 = *(const float4*)(base + (size_t)(x + 360)*NZ + zh*4);
    const float4 q3 = *(const float4*)(base + (size_t)(x + 540)*NZ + zh*4);
    float4 s0v, s2v, av, bv;
    s0v.x=q0.x+q1.x+q2.x+q3.x; s2v.x=q0.x-q1.x+q2.x-q3.x; av.x=q0.x-q2.x; bv.x=q1.x-q3.x;
    s0v.y=q0.y+q1.y+q2.y+q3.y; s2v.y=q0.y-q1.y+q2.y-q3.y; av.y=q0.y-q2.y; bv.y=q1.y-q3.y;
    s0v.z=q0.z+q1.z+q2.z+q3.z; s2v.z=q0.z-q1.z+q2.z-q3.z; av.z=q0.z-q2.z; bv.z=q1.z-q3.z;
    s0v.w=q0.w+q1.w+q2.w+q3.w; s2v.w=q0.w-q1.w+q2.w-q3.w; av.w=q0.w-q2.w; bv.w=q1.w-q3.w;
    *(float4*)&S0[x][zh*4] = s0v;
    *(float4*)&S2[x][zh*4] = s2v;
    *(float4*)&AB[x][zh*4+0][0] = make_float4(av.x, bv.x, av.y, bv.y);
    *(float4*)&AB[x][zh*4+2][0] = make_float4(av.z, bv.z, av.w, bv.w);
  }
  __syncthreads();

  // ---- analysis: thread = (kv 0..191, zh 0..1); one k, 4 z, one chain ----
  {
    const int zh = tid & 1;
    const int kv = tid >> 1;            // 0..191; waves 0-2 even-class, 3-5 odd
    const bool isodd = (kv >= 96);
    const int m  = isodd ? kv - 96 : kv;
    const int ke0 = k0 + (k0 & 1);      // first even >= k0
    const int ko0 = k0 + 1 - (k0 & 1);  // first odd  >= k0
    const int k  = (isodd ? ko0 : ke0) + 2*m;
    if (k <= k1) {
      float dc, ds; sincosf((float)k * TH, &ds, &dc);
      float c = 1.f, s = 0.f;
      float c0a=0,s0a=0,c1a=0,s1a=0,c2a=0,s2a=0,c3a=0,s3a=0;
      if (!isodd) {
        const float* Sp = ((k & 3) == 0) ? &S0[0][0] : &S2[0][0];
        for (int x = 0; x < 180; ++x) {
          const float4 v4 = *(const float4*)&Sp[x*8 + zh*4];
          c0a = fmaf(v4.x, c, c0a); s0a = fmaf(v4.x, s, s0a);
          c1a = fmaf(v4.y, c, c1a); s1a = fmaf(v4.y, s, s1a);
          c2a = fmaf(v4.z, c, c2a); s2a = fmaf(v4.z, s, s2a);
          c3a = fmaf(v4.w, c, c3a); s3a = fmaf(v4.w, s, s3a);
          const float nc = fmaf(c, dc, -s*ds);
          s = fmaf(s, dc, c*ds); c = nc;
        }
      } else {
        const float sg = ((k & 3) == 1) ? 1.0f : -1.0f;
        for (int x = 0; x < 180; ++x) {
          const float4 p0 = *(const float4*)&AB[x][zh*4+0][0]; // A0,B0,A1,B1
          const float4 p1 = *(const float4*)&AB[x][zh*4+2][0]; // A2,B2,A3,B3
          const float t0 = sg*p0.y, t1 = sg*p0.w, t2 = sg*p1.y, t3 = sg*p1.w;
          c0a = fmaf(p0.x, c, fmaf(t0, -s, c0a)); s0a = fmaf(p0.x, s, fmaf(t0, c, s0a));
          c1a = fmaf(p0.z, c, fmaf(t1, -s, c1a)); s1a = fmaf(p0.z, s, fmaf(t1, c, s1a));
          c2a = fmaf(p1.x, c, fmaf(t2, -s, c2a)); s2a = fmaf(p1.x, s, fmaf(t2, c, s2a));
          c3a = fmaf(p1.z, c, fmaf(t3, -s, c3a)); s3a = fmaf(p1.z, s, fmaf(t3, c, s3a));
          const float nc = fmaf(c, dc, -s*ds);
          s = fmaf(s, dc, c*ds); c = nc;
        }
      }
      const float w = (k==0 || k==360) ? 1.0f : 2.0f;
      const int r = k - k0;
      *(float4*)&SD[r][zh*4+0][0] = make_float4(w*c0a, w*s0a, w*c1a, w*s1a);
      *(float4*)&SD[r][zh*4+2][0] = make_float4(w*c2a, w*s2a, w*c3a, w*s3a);
    }
  }
  __syncthreads();

  // ---- synthesis: thread = (x' 0..179, z-half 0..1), 4 z each ----
  if (tid < 360) {
    const int x  = tid % 180;
    const int zh = tid / 180;
    float HreE[2][4]; float Hro[2][4]; float Hio[2][4];
    #pragma unroll
    for (int i = 0; i < 2; ++i)
      #pragma unroll
      for (int j = 0; j < 4; ++j) { HreE[i][j]=0.f; Hro[i][j]=0.f; Hio[i][j]=0.f; }

    const int m4 = (4*x) % 720;
    float dstep_s, dstep_c; sincosf((float)m4 * TH, &dstep_s, &dstep_c);

    // even residues r=0,2: only Re needed
    #pragma unroll
    for (int ri = 0; ri < 2; ++ri) {
      const int r = ri*2;
      const int kst = k0 + ((r - (k0 & 3) + 4) & 3);
      if (kst > k1) continue;
      int mm = (kst * x) % 720;
      float sv, cv; sincosf((float)mm * TH, &sv, &cv);
      for (int k = kst; k <= k1; k += 4) {
        const float4 d01 = *(const float4*)&SD[k - k0][zh*4 + 0][0];
        const float4 d23 = *(const float4*)&SD[k - k0][zh*4 + 2][0];
        HreE[ri][0] = fmaf(d01.x, cv, fmaf(d01.y, sv, HreE[ri][0]));
        HreE[ri][1] = fmaf(d01.z, cv, fmaf(d01.w, sv, HreE[ri][1]));
        HreE[ri][2] = fmaf(d23.x, cv, fmaf(d23.y, sv, HreE[ri][2]));
        HreE[ri][3] = fmaf(d23.z, cv, fmaf(d23.w, sv, HreE[ri][3]));
        float nc = fmaf(cv, dstep_c, -sv*dstep_s);   // forward rotation +4x*theta
        float ns = fmaf(sv, dstep_c,  cv*dstep_s);
        cv = nc; sv = ns;
      }
    }
    // odd residues r=1,3: Re and Im
    #pragma unroll
    for (int ri = 0; ri < 2; ++ri) {
      const int r = ri*2 + 1;
      const int kst = k0 + ((r - (k0 & 3) + 4) & 3);
      if (kst > k1) continue;
      int mm = (kst * x) % 720;
      float sv, cv; sincosf((float)mm * TH, &sv, &cv);
      for (int k = kst; k <= k1; k += 4) {
        const float4 d01 = *(const float4*)&SD[k - k0][zh*4 + 0][0];
        const float4 d23 = *(const float4*)&SD[k - k0][zh*4 + 2][0];
        Hro[ri][0] = fmaf(d01.x, cv, fmaf(d01.y, sv, Hro[ri][0]));
        Hio[ri][0] = fmaf(d01.y, cv, fmaf(-d01.x, sv, Hio[ri][0]));
        Hro[ri][1] = fmaf(d01.z, cv, fmaf(d01.w, sv, Hro[ri][1]));
        Hio[ri][1] = fmaf(d01.w, cv, fmaf(-d01.z, sv, Hio[ri][1]));
        Hro[ri][2] = fmaf(d23.x, cv, fmaf(d23.y, sv, Hro[ri][2]));
        Hio[ri][2] = fmaf(d23.y, cv, fmaf(-d23.x, sv, Hio[ri][2]));
        Hro[ri][3] = fmaf(d23.z, cv, fmaf(d23.w, sv, Hro[ri][3]));
        Hio[ri][3] = fmaf(d23.w, cv, fmaf(-d23.z, sv, Hio[ri][3]));
        float nc = fmaf(cv, dstep_c, -sv*dstep_s);   // forward rotation +4x*theta
        float ns = fmaf(sv, dstep_c,  cv*dstep_s);
        cv = nc; sv = ns;
      }
    }

    const float inv = 1.0f/720.0f;
    float o[4][4];
    float4 s0v, s2v, ab01, ab23;
    if (!keep) {
      s0v  = *(const float4*)&S0[x][zh*4];
      s2v  = *(const float4*)&S2[x][zh*4];
      ab01 = *(const float4*)&AB[x][zh*4+0][0];
      ab23 = *(const float4*)&AB[x][zh*4+2][0];
    }
    #pragma unroll
    for (int j = 0; j < 4; ++j) {
      const float h0  = HreE[0][j], h2 = HreE[1][j];
      const float h1r = Hro[0][j],  h1i = Hio[0][j];
      const float h3r = Hro[1][j],  h3i = Hio[1][j];
      float l0 = (h0 + h1r + h2 + h3r) * inv;
      float l1 = (h0 + h1i - h2 - h3i) * inv;
      float l2 = (h0 - h1r + h2 - h3r) * inv;
      float l3 = (h0 - h1i - h2 + h3i) * inv;
      if (!keep) {
        const float s0j = (j==0)?s0v.x:(j==1)?s0v.y:(j==2)?s0v.z:s0v.w;
        const float s2j = (j==0)?s2v.x:(j==1)?s2v.y:(j==2)?s2v.z:s2v.w;
        const float aj  = (j==0)?ab01.x:(j==1)?ab01.z:(j==2)?ab23.x:ab23.z;
        const float bj  = (j==0)?ab01.y:(j==1)?ab01.w:(j==2)?ab23.y:ab23.w;
        const float sp = 0.25f*(s0j + s2j), sm = 0.25f*(s0j - s2j);
        const float q0v = sp + 0.5f*aj, q2v = sp - 0.5f*aj;
        const float q1v = sm + 0.5f*bj, q3v = sm - 0.5f*bj;
        l0 = q0v - l0; l1 = q1v - l1; l2 = q2v - l2; l3 = q3v - l3;
      }
      o[0][j] = fminf(fmaxf(l0, -clipv), clipv);
      o[1][j] = fminf(fmaxf(l1, -clipv), clipv);
      o[2][j] = fminf(fmaxf(l2, -clipv), clipv);
      o[3][j] = fminf(fmaxf(l3, -clipv), clipv);
    }
    #pragma unroll
    for (int j = 0; j < 4; ++j) {
      *(float4*)(base + (size_t)(x + 180*j)*NZ + zh*4) =
          make_float4(o[j][0], o[j][1], o[j][2], o[j][3]);
    }
  }
}

// -------------------- kernel 3: polar filter for dpsdt (3D) ----------------
__global__ __launch_bounds__(384) void k_filter_ps(float* __restrict__ dps) {
  __shared__ float  f[NX];
  __shared__ float2 tw[NX];
  __shared__ float  sc[184], ss[184];
  const int tid = threadIdx.x;
  const int row = blockIdx.x;       // 0..719 = b*360+y
  const int y = row % NY;
  float* base = dps + (size_t)row*NX;
  for (int t = tid; t < NX; t += 384) {
    float a = (float)t * (float)(2.0*M_PI/720.0);
    float sv, cv; sincosf(a, &sv, &cv);
    tw[t] = make_float2(cv, sv);
    f[t] = base[t];
  }
  int k0, k1; bool keepmode;
  filter_band(y, k0, k1, keepmode);
  const int nk = k1 - k0 + 1;
  __syncthreads();

  if (tid < nk) {
    const int k = k0 + tid;
    float ac=0.f, as=0.f; int idx=0;
    for (int xx=0; xx<NX; ++xx) {
      const float fv = f[xx];
      const float2 t2 = tw[idx];
      ac = fmaf(fv, t2.x, ac); as = fmaf(fv, t2.y, as);
      idx += k; if (idx >= NX) idx -= NX;
    }
    sc[tid]=ac; ss[tid]=as;
  }
  __syncthreads();

  if (tid < 360) {
    const int x0 = tid, x1 = tid + 360;
    const int t0 = (x0 * k0) % NX;
    const int t1 = (x1 * k0) % NX;
    float c0 = tw[t0].x, s0 = tw[t0].y;
    float c1 = tw[t1].x, s1 = tw[t1].y;
    const float dc0 = tw[x0].x, dn0 = tw[x0].y;
    const float dc1 = tw[x1].x, dn1 = tw[x1].y;
    float a0 = 0.f, a1 = 0.f;
    for (int kk = 0; kk < nk; ++kk) {
      const int k = k0 + kk;
      const float w = (k==0 || k==360) ? 1.0f : 2.0f;
      a0 = fmaf(sc[kk], w*c0, fmaf(ss[kk], w*s0, a0));
      a1 = fmaf(sc[kk], w*c1, fmaf(ss[kk], w*s1, a1));
      float n0 = c0*dc0 - s0*dn0; s0 = c0*dn0 + s0*dc0; c0 = n0;
      float n1 = c1*dc1 - s1*dn1; s1 = c1*dn1 + s1*dc1; c1 = n1;
    }
    const float inv = 1.0f/720.0f;
    float o0 = keepmode ? a0*inv : f[x0] - a0*inv;
    float o1 = keepmode ? a1*inv : f[x1] - a1*inv;
    o0 = fminf(fmaxf(o0, -0.5f), 0.5f);
    o1 = fminf(fmaxf(o1, -0.5f), 0.5f);
    base[x0] = o0;
    base[x1] = o1;
  }
}

// -------------------- host --------------------
extern "C" void kernel_launch(void* const* d_in, const int* in_sizes, int n_in,
                              void* d_out, int out_size, void* d_ws, size_t ws_size,
                              hipStream_t stream) {
  (void)in_sizes; (void)n_in; (void)d_ws; (void)ws_size; (void)out_size;
  const float* u  = (const float*)d_in[0];
  const float* v  = (const float*)d_in[1];
  const float* T  = (const float*)d_in[2];
  const float* ps = (const float*)d_in[4];
  const float* Rp = (const float*)d_in[6];

  float* out = (float*)d_out;
  float* du  = out;
  float* dv  = out + (size_t)NPTS;
  float* dT  = out + (size_t)2*NPTS;
  float* dq  = out + (size_t)3*NPTS;   // zeroed by k_tend
  float* dps = out + (size_t)4*NPTS;

  k_tend<<<NCOL/8, 256, 0, stream>>>(u, v, T, ps, Rp, du, dv, dT, dq, dps);
  k_filter4b<<<3*NB*NY*4, 384, 0, stream>>>(du, dv, dT);
  k_filter_ps<<<NB*NY, 384, 0, stream>>>(dps);
}

// Round 7
// 644.884 us; speedup vs baseline: 1.0947x; 1.0773x over previous
//
#include <hip/hip_runtime.h>
#include <math.h>

#define NB 2
#define NY 360
#define NX 720
#define NZ 32
#define NPTS (NB*NY*NX*NZ)     // 16,588,800
#define NCOL (NB*NY*NX)        // 518,400

__device__ __forceinline__ int i4(int b,int y,int x,int z){ return (((b*NY)+y)*NX+x)*NZ+z; }
__device__ __forceinline__ int i3(int b,int y,int x){ return ((b*NY)+y)*NX+x; }

#define F_RAD   6371000.0f
#define F_OMEGA 7.292e-5f
#define F_CP    1004.0f
#define F_DLAT  ((float)(M_PI/360.0))                 /* == dlon */
#define F_DYR   ((float)(M_PI/360.0*6371000.0))      /* dlat*RAD */
#define F_HPI   ((float)(M_PI/2.0))
#define TH      ((float)(2.0*M_PI/720.0))

// -------------------- kernel 1: div_h = du/dx + dv/dy --------------------
__global__ __launch_bounds__(256) void k_divh(const float* __restrict__ u,
                                              const float* __restrict__ v,
                                              float* __restrict__ divh) {
  int gid = blockIdx.x*256 + threadIdx.x;          // exact: 64800*256 = NPTS
  int z  = gid & 31;
  int x  = (gid >> 5) % NX;
  int by = gid / (NX*NZ);
  int y  = by % NY;
  int b  = by / NY;
  float lat = -F_HPI + (y+0.5f)*F_DLAT;
  float cl  = cosf(lat);
  float invdx = 0.5f/(F_DLAT*F_RAD*cl);
  int xp = (x==NX-1)?0:x+1, xm = (x==0)?NX-1:x-1;
  float dudx = (u[i4(b,y,xp,z)] - u[i4(b,y,xm,z)]) * invdx;
  float dvdy;
  if (y == 0)          dvdy = (v[i4(b,1,x,z)]    - v[i4(b,0,x,z)])    * (1.0f/F_DYR);
  else if (y == NY-1)  dvdy = (v[i4(b,NY-1,x,z)] - v[i4(b,NY-2,x,z)]) * (1.0f/F_DYR);
  else                 dvdy = (v[i4(b,y+1,x,z)]  - v[i4(b,y-1,x,z)])  * (0.5f/F_DYR);
  divh[gid] = dudx + dvdy;
}

// -------------------- kernel 2: all raw tendencies --------------------
__global__ __launch_bounds__(256) void k_tend(
    const float* __restrict__ u, const float* __restrict__ v,
    const float* __restrict__ T, const float* __restrict__ ps,
    const float* __restrict__ Rp, const float* __restrict__ divh,
    float* __restrict__ du, float* __restrict__ dv,
    float* __restrict__ dT, float* __restrict__ dps) {
  const int tid = threadIdx.x;
  const int z   = tid & 31;
  const int col = blockIdx.x*8 + (tid>>5);         // exact: 64800*8 = NCOL
  const int x = col % NX;
  const int y = (col / NX) % NY;
  const int b = col / (NX*NY);
  const float R = Rp[0];

  const int xp = (x==NX-1)?0:x+1, xm = (x==0)?NX-1:x-1;
  const int ycm = (y>0)? y-1 : 0;
  const int ycp = (y<NY-1)? y+1 : NY-1;
  const bool y0 = (y==0), yN = (y==NY-1);

  const float lat  = -F_HPI + (y+0.5f)*F_DLAT;
  const float cl   = cosf(lat);
  const float fcor = 2.0f*F_OMEGA*sinf(lat);
  const float sx     = F_DLAT*F_RAD*cl;
  const float invdx  = 0.5f/sx;
  const float inv2dy = 0.5f/F_DYR;
  const float inv1dy = 1.0f/F_DYR;
  const float invsx2 = 1.0f/(sx*sx);
  const float invsy2 = 1.0f/(F_DYR*F_DYR);
  const float bk  = (z + 0.5f)/32.0f;
  const float dsv = 1.0f/32.0f;

  const int ic  = i4(b,y,x,z),   ixp = i4(b,y,xp,z), ixm = i4(b,y,xm,z);
  const int iyp = i4(b,ycp,x,z), iym = i4(b,ycm,x,z);

  const float uc=u[ic], uxp=u[ixp], uxm=u[ixm], uyp=u[iyp], uym=u[iym];
  const float vc=v[ic], vxp=v[ixp], vxm=v[ixm], vyp=v[iyp], vym=v[iym];
  const float Tc=T[ic], Txp=T[ixp], Txm=T[ixm], Typ=T[iyp], Tym=T[iym];
  const float Dc=divh[ic], Dxp=divh[ixp], Dxm=divh[ixm], Dyp=divh[iyp], Dym=divh[iym];
  const float psc=ps[i3(b,y,x)],   psxp=ps[i3(b,y,xp)], psxm=ps[i3(b,y,xm)];
  const float psyp=ps[i3(b,ycp,x)], psym=ps[i3(b,ycm,x)];

  auto dfy = [&](float fc_, float fyp_, float fym_) -> float {
    if (y0) return (fyp_ - fc_) * inv1dy;
    if (yN) return (fc_ - fym_) * inv1dy;
    return (fyp_ - fym_) * inv2dy;
  };
  auto lap = [&](float fc_, float fxp_, float fxm_, float fyp_, float fym_) -> float {
    float d2x = (fxp_ + fxm_ - 2.0f*fc_) * invsx2;
    float d2y = (y0||yN) ? 0.0f : (fyp_ + fym_ - 2.0f*fc_) * invsy2;
    return d2x + d2y;
  };
  auto sufscan = [&](float vv) -> float {   // vv[z] = sum_{j>=z}
    #pragma unroll
    for (int d=1; d<32; d<<=1) { float t = __shfl_down(vv, d, 32); if (z+d<32) vv += t; }
    return vv;
  };
  auto prescan = [&](float vv) -> float {   // vv[z] = sum_{j<=z}
    #pragma unroll
    for (int d=1; d<32; d<<=1) { float t = __shfl_up(vv, d, 32); if (z>=d) vv += t; }
    return vv;
  };
  auto vg = [&](float fc_) -> float {       // d/dsigma
    float fzp = __shfl_down(fc_,1,32), fzm = __shfl_up(fc_,1,32);
    if (z==0)  return (fzp - fc_) * 32.0f;
    if (z==31) return (fc_ - fzm) * 32.0f;
    return (fzp - fzm) * 16.0f;
  };

  const float rz = dsv / bk;
  const float phic  = sufscan(R*Tc*rz);
  const float phixp = sufscan(R*Txp*rz);
  const float phixm = sufscan(R*Txm*rz);
  const float phiyp = sufscan(R*Typ*rz);
  const float phiym = sufscan(R*Tym*rz);

  const float dudx = (uxp-uxm)*invdx, dvdx = (vxp-vxm)*invdx, dTdx = (Txp-Txm)*invdx;
  const float dphidx = (phixp-phixm)*invdx;
  const float dudy = dfy(uc,uyp,uym), dvdy_ = dfy(vc,vyp,vym), dTdy = dfy(Tc,Typ,Tym);
  const float dphidy = dfy(phic,phiyp,phiym);
  const float dpsdx = (psxp-psxm)*invdx, dpsdy = dfy(psc,psyp,psym);
  const float gdivx = (Dxp-Dxm)*invdx,  gdivy = dfy(Dc,Dyp,Dym);

  const float mass = Dc*psc + uc*dpsdx + vc*dpsdy;
  float Ipre = prescan(mass) * dsv;
  const float Itot = __shfl(Ipre, 31, 32);
  const float sigd = (bk*Itot - Ipre) / (psc + 1e-8f);

  const float vgu = vg(uc), vgv = vg(vc), vgT = vg(Tc);

  const float pfac = R*Tc*bk/(bk*psc + 1e-8f);
  const float pgfu = -dphidx - pfac*dpsdx;
  const float pgfv = -dphidy - pfac*dpsdy;
  const float cf2  = fmaxf(cl*cl, 0.01f);
  const float nudiv = 500000.0f*cf2, nuh = 100000.0f*cf2;
  const float lapu = lap(uc,uxp,uxm,uyp,uym);
  const float lapv = lap(vc,vxp,vxm,vyp,vym);
  const float lapT = lap(Tc,Txp,Txm,Typ,Tym);
  const float adiab = R*Tc/(bk*psc*F_CP + 1e-8f) * (sigd*psc);

  float dut = -(uc*dudx + vc*dudy)  - sigd*vgu + fcor*vc + pgfu + nuh*lapu - 1e-5f*uc + nudiv*gdivx;
  float dvt = -(uc*dvdx + vc*dvdy_) - sigd*vgv - fcor*uc + pgfv + nuh*lapv - 1e-5f*vc + nudiv*gdivy;
  float dTt = -(uc*dTdx + vc*dTdy)  - sigd*vgT + adiab + nuh*lapT;

  du[ic] = dut; dv[ic] = dvt; dT[ic] = dTt;
  if (z == 0) dps[i3(b,y,x)] = -Itot;
}

// -------------------- kernel 3: zero dqdt (doubled as div_h scratch) ------
__global__ __launch_bounds__(256) void k_zero(float4* __restrict__ p) {
  p[blockIdx.x*256 + threadIdx.x] = make_float4(0.f,0.f,0.f,0.f);
}

// -------------------- polar filter helpers --------------------
__device__ __forceinline__ void filter_band(int y, int& k0, int& k1, bool& keepmode) {
  float lat = -F_HPI + (y+0.5f)*F_DLAT;
  float cut = fmaxf(360.0f*cosf(lat), 1.0f);
  int M = (int)floorf(cut);
  keepmode = (M <= 179);
  k0 = keepmode ? 0 : (M+1);
  k1 = keepmode ? M : 360;
}

// -------------------- kernel 4: folded-DFT polar filter, 3 fields ---------
// Analysis thread = (ks 0..95, xh 0..1, zh 0..1). Per k-parity, cnt = number
// of band k's. cnt<=48 (common mid-lat): xh lanes split x 90/90 and combine
// via shfl_xor(2) — halves chains, doubles active lanes. cnt>48 (polar/60°):
// xh lanes take k and k+96, full 180-x chains (dual mode). Both branches are
// block-uniform. XCD-chunked block swizzle keeps zq-siblings on one XCD.
#define FKMAX 180
__global__ __launch_bounds__(384) void k_filter4b(
    float* __restrict__ du, float* __restrict__ dv, float* __restrict__ dT) {
  __shared__ float S0[180][8];
  __shared__ float S2[180][8];
  __shared__ float AB[180][8][2];     // interleaved A,B
  __shared__ float SD[FKMAX][8][2];   // w*(c_k, s_k) per band index, per z

  const int tid  = threadIdx.x;
  // bijective XCD-chunk swizzle: 8640 = 8 * 1080
  const int bid  = (blockIdx.x & 7) * 1080 + (blockIdx.x >> 3);
  const int zq   = bid & 3;
  const int rest = bid >> 2;
  const int by   = rest % (NB*NY);
  const int fld  = rest / (NB*NY);
  const int y = by % NY, b = by / NY;
  float* fptr = (fld==0)? du : (fld==1)? dv : dT;
  const float clipv = (fld==2)? 0.01f : 0.02f;
  float* base = fptr + ((size_t)(b*NY+y)*NX)*NZ + zq*8;

  int k0, k1; bool keep;
  filter_band(y, k0, k1, keep);

  // ---- load + fold ----
  if (tid < 360) {
    const int x  = tid % 180;
    const int zh = tid / 180;                       // 0/1 -> z offset 4*zh
    const float4 q0 = *(const float4*)(base + (size_t)(x      )*NZ + zh*4);
    const float4 q1 = *(const float4*)(base + (size_t)(x + 180)*NZ + zh*4);
    const float4 q2 = *(const float4*)(base + (size_t)(x + 360)*NZ + zh*4);
    const float4 q3 = *(const float4*)(base + (size_t)(x + 540)*NZ + zh*4);
    float4 s0v, s2v, av, bv;
    s0v.x=q0.x+q1.x+q2.x+q3.x; s2v.x=q0.x-q1.x+q2.x-q3.x; av.x=q0.x-q2.x; bv.x=q1.x-q3.x;
    s0v.y=q0.y+q1.y+q2.y+q3.y; s2v.y=q0.y-q1.y+q2.y-q3.y; av.y=q0.y-q2.y; bv.y=q1.y-q3.y;
    s0v.z=q0.z+q1.z+q2.z+q3.z; s2v.z=q0.z-q1.z+q2.z-q3.z; av.z=q0.z-q2.z; bv.z=q1.z-q3.z;
    s0v.w=q0.w+q1.w+q2.w+q3.w; s2v.w=q0.w-q1.w+q2.w-q3.w; av.w=q0.w-q2.w; bv.w=q1.w-q3.w;
    *(float4*)&S0[x][zh*4] = s0v;
    *(float4*)&S2[x][zh*4] = s2v;
    *(float4*)&AB[x][zh*4+0][0] = make_float4(av.x, bv.x, av.y, bv.y);
    *(float4*)&AB[x][zh*4+2][0] = make_float4(av.z, bv.z, av.w, bv.w);
  }
  __syncthreads();

  // ---- analysis ----
  {
    const int zh = tid & 1;
    const int xh = (tid >> 1) & 1;
    const int ks = tid >> 2;            // 0..95
    const bool isodd = (ks >= 48);
    const int slot = isodd ? ks - 48 : ks;
    const int ke0 = k0 + (k0 & 1);      // first even >= k0
    const int ko0 = k0 | 1;             // first odd  >= k0
    const int kbase = isodd ? ko0 : ke0;
    const int cnt   = (k1 >= kbase) ? (((k1 - kbase) >> 1) + 1) : 0;
    const bool dual = (cnt > 48);
    int k, x0, xe; bool act;
    if (dual) { k = kbase + 2*(slot + 48*xh); x0 = 0;     xe = 180;     act = (k <= k1); }
    else      { k = kbase + 2*slot;           x0 = 90*xh; xe = x0 + 90; act = (slot < cnt); }

    float ac0=0,as0=0,ac1=0,as1=0,ac2=0,as2=0,ac3=0,as3=0;
    if (act) {
      float dc, ds; sincosf((float)k * TH, &ds, &dc);
      float c, s;   sincosf((float)((k * x0) % 720) * TH, &s, &c);
      if (!isodd) {
        const float* Sp = ((k & 3) == 0) ? &S0[0][0] : &S2[0][0];
        for (int x = x0; x < xe; ++x) {
          const float4 v4 = *(const float4*)&Sp[x*8 + zh*4];
          ac0 = fmaf(v4.x, c, ac0); as0 = fmaf(v4.x, s, as0);
          ac1 = fmaf(v4.y, c, ac1); as1 = fmaf(v4.y, s, as1);
          ac2 = fmaf(v4.z, c, ac2); as2 = fmaf(v4.z, s, as2);
          ac3 = fmaf(v4.w, c, ac3); as3 = fmaf(v4.w, s, as3);
          const float nc = fmaf(c, dc, -s*ds);
          s = fmaf(s, dc, c*ds); c = nc;
        }
      } else {
        const float sg = ((k & 3) == 1) ? 1.0f : -1.0f;
        for (int x = x0; x < xe; ++x) {
          const float4 p0 = *(const float4*)&AB[x][zh*4+0][0]; // A0,B0,A1,B1
          const float4 p1 = *(const float4*)&AB[x][zh*4+2][0]; // A2,B2,A3,B3
          const float sgc = sg*c, sgs = sg*s;
          ac0 = fmaf(p0.x, c, fmaf(p0.y, -sgs, ac0)); as0 = fmaf(p0.x, s, fmaf(p0.y, sgc, as0));
          ac1 = fmaf(p0.z, c, fmaf(p0.w, -sgs, ac1)); as1 = fmaf(p0.z, s, fmaf(p0.w, sgc, as1));
          ac2 = fmaf(p1.x, c, fmaf(p1.y, -sgs, ac2)); as2 = fmaf(p1.x, s, fmaf(p1.y, sgc, as2));
          ac3 = fmaf(p1.z, c, fmaf(p1.w, -sgs, ac3)); as3 = fmaf(p1.z, s, fmaf(p1.w, sgc, as3));
          const float nc = fmaf(c, dc, -s*ds);
          s = fmaf(s, dc, c*ds); c = nc;
        }
      }
    }
    if (!dual) {
      // combine x-halves: pair lanes differ by lane distance 2 (same wave)
      ac0 += __shfl_xor(ac0, 2); as0 += __shfl_xor(as0, 2);
      ac1 += __shfl_xor(ac1, 2); as1 += __shfl_xor(as1, 2);
      ac2 += __shfl_xor(ac2, 2); as2 += __shfl_xor(as2, 2);
      ac3 += __shfl_xor(ac3, 2); as3 += __shfl_xor(as3, 2);
    }
    if (act) {
      const float w = (k==0 || k==360) ? 1.0f : 2.0f;
      const int r = k - k0;
      if (dual) {
        *(float4*)&SD[r][zh*4+0][0] = make_float4(w*ac0, w*as0, w*ac1, w*as1);
        *(float4*)&SD[r][zh*4+2][0] = make_float4(w*ac2, w*as2, w*ac3, w*as3);
      } else if (xh == 0) {
        *(float4*)&SD[r][zh*4+0][0] = make_float4(w*ac0, w*as0, w*ac1, w*as1);
      } else {
        *(float4*)&SD[r][zh*4+2][0] = make_float4(w*ac2, w*as2, w*ac3, w*as3);
      }
    }
  }
  __syncthreads();

  // ---- synthesis: thread = (x' 0..179, z-half 0..1), 4 z each ----
  if (tid < 360) {
    const int x  = tid % 180;
    const int zh = tid / 180;
    float HreE[2][4]; float Hro[2][4]; float Hio[2][4];
    #pragma unroll
    for (int i = 0; i < 2; ++i)
      #pragma unroll
      for (int j = 0; j < 4; ++j) { HreE[i][j]=0.f; Hro[i][j]=0.f; Hio[i][j]=0.f; }

    const int m4 = (4*x) % 720;
    float dstep_s, dstep_c; sincosf((float)m4 * TH, &dstep_s, &dstep_c);

    // even residues r=0,2: only Re needed
    #pragma unroll
    for (int ri = 0; ri < 2; ++ri) {
      const int r = ri*2;
      const int kst = k0 + ((r - (k0 & 3) + 4) & 3);
      if (kst > k1) continue;
      int mm = (kst * x) % 720;
      float sv, cv; sincosf((float)mm * TH, &sv, &cv);
      for (int k = kst; k <= k1; k += 4) {
        const float4 d01 = *(const float4*)&SD[k - k0][zh*4 + 0][0];
        const float4 d23 = *(const float4*)&SD[k - k0][zh*4 + 2][0];
        HreE[ri][0] = fmaf(d01.x, cv, fmaf(d01.y, sv, HreE[ri][0]));
        HreE[ri][1] = fmaf(d01.z, cv, fmaf(d01.w, sv, HreE[ri][1]));
        HreE[ri][2] = fmaf(d23.x, cv, fmaf(d23.y, sv, HreE[ri][2]));
        HreE[ri][3] = fmaf(d23.z, cv, fmaf(d23.w, sv, HreE[ri][3]));
        float nc = fmaf(cv, dstep_c, -sv*dstep_s);   // forward rotation +4x*theta
        float ns = fmaf(sv, dstep_c,  cv*dstep_s);
        cv = nc; sv = ns;
      }
    }
    // odd residues r=1,3: Re and Im
    #pragma unroll
    for (int ri = 0; ri < 2; ++ri) {
      const int r = ri*2 + 1;
      const int kst = k0 + ((r - (k0 & 3) + 4) & 3);
      if (kst > k1) continue;
      int mm = (kst * x) % 720;
      float sv, cv; sincosf((float)mm * TH, &sv, &cv);
      for (int k = kst; k <= k1; k += 4) {
        const float4 d01 = *(const float4*)&SD[k - k0][zh*4 + 0][0];
        const float4 d23 = *(const float4*)&SD[k - k0][zh*4 + 2][0];
        Hro[ri][0] = fmaf(d01.x, cv, fmaf(d01.y, sv, Hro[ri][0]));
        Hio[ri][0] = fmaf(d01.y, cv, fmaf(-d01.x, sv, Hio[ri][0]));
        Hro[ri][1] = fmaf(d01.z, cv, fmaf(d01.w, sv, Hro[ri][1]));
        Hio[ri][1] = fmaf(d01.w, cv, fmaf(-d01.z, sv, Hio[ri][1]));
        Hro[ri][2] = fmaf(d23.x, cv, fmaf(d23.y, sv, Hro[ri][2]));
        Hio[ri][2] = fmaf(d23.y, cv, fmaf(-d23.x, sv, Hio[ri][2]));
        Hro[ri][3] = fmaf(d23.z, cv, fmaf(d23.w, sv, Hro[ri][3]));
        Hio[ri][3] = fmaf(d23.w, cv, fmaf(-d23.z, sv, Hio[ri][3]));
        float nc = fmaf(cv, dstep_c, -sv*dstep_s);   // forward rotation +4x*theta
        float ns = fmaf(sv, dstep_c,  cv*dstep_s);
        cv = nc; sv = ns;
      }
    }

    const float inv = 1.0f/720.0f;
    float o[4][4];
    float4 s0v, s2v, ab01, ab23;
    if (!keep) {
      s0v  = *(const float4*)&S0[x][zh*4];
      s2v  = *(const float4*)&S2[x][zh*4];
      ab01 = *(const float4*)&AB[x][zh*4+0][0];
      ab23 = *(const float4*)&AB[x][zh*4+2][0];
    }
    #pragma unroll
    for (int j = 0; j < 4; ++j) {
      const float h0  = HreE[0][j], h2 = HreE[1][j];
      const float h1r = Hro[0][j],  h1i = Hio[0][j];
      const float h3r = Hro[1][j],  h3i = Hio[1][j];
      float l0 = (h0 + h1r + h2 + h3r) * inv;
      float l1 = (h0 + h1i - h2 - h3i) * inv;
      float l2 = (h0 - h1r + h2 - h3r) * inv;
      float l3 = (h0 - h1i - h2 + h3i) * inv;
      if (!keep) {
        const float s0j = (j==0)?s0v.x:(j==1)?s0v.y:(j==2)?s0v.z:s0v.w;
        const float s2j = (j==0)?s2v.x:(j==1)?s2v.y:(j==2)?s2v.z:s2v.w;
        const float aj  = (j==0)?ab01.x:(j==1)?ab01.z:(j==2)?ab23.x:ab23.z;
        const float bj  = (j==0)?ab01.y:(j==1)?ab01.w:(j==2)?ab23.y:ab23.w;
        const float sp = 0.25f*(s0j + s2j), sm = 0.25f*(s0j - s2j);
        const float q0v = sp + 0.5f*aj, q2v = sp - 0.5f*aj;
        const float q1v = sm + 0.5f*bj, q3v = sm - 0.5f*bj;
        l0 = q0v - l0; l1 = q1v - l1; l2 = q2v - l2; l3 = q3v - l3;
      }
      o[0][j] = fminf(fmaxf(l0, -clipv), clipv);
      o[1][j] = fminf(fmaxf(l1, -clipv), clipv);
      o[2][j] = fminf(fmaxf(l2, -clipv), clipv);
      o[3][j] = fminf(fmaxf(l3, -clipv), clipv);
    }
    #pragma unroll
    for (int j = 0; j < 4; ++j) {
      *(float4*)(base + (size_t)(x + 180*j)*NZ + zh*4) =
          make_float4(o[j][0], o[j][1], o[j][2], o[j][3]);
    }
  }
}

// -------------------- kernel 5: polar filter for dpsdt (3D) ----------------
__global__ __launch_bounds__(384) void k_filter_ps(float* __restrict__ dps) {
  __shared__ float  f[NX];
  __shared__ float2 tw[NX];
  __shared__ float  sc[184], ss[184];
  const int tid = threadIdx.x;
  const int row = blockIdx.x;       // 0..719 = b*360+y
  const int y = row % NY;
  float* base = dps + (size_t)row*NX;
  for (int t = tid; t < NX; t += 384) {
    float a = (float)t * (float)(2.0*M_PI/720.0);
    float sv, cv; sincosf(a, &sv, &cv);
    tw[t] = make_float2(cv, sv);
    f[t] = base[t];
  }
  int k0, k1; bool keepmode;
  filter_band(y, k0, k1, keepmode);
  const int nk = k1 - k0 + 1;
  __syncthreads();

  if (tid < nk) {
    const int k = k0 + tid;
    float ac=0.f, as=0.f; int idx=0;
    for (int xx=0; xx<NX; ++xx) {
      const float fv = f[xx];
      const float2 t2 = tw[idx];
      ac = fmaf(fv, t2.x, ac); as = fmaf(fv, t2.y, as);
      idx += k; if (idx >= NX) idx -= NX;
    }
    sc[tid]=ac; ss[tid]=as;
  }
  __syncthreads();

  if (tid < 360) {
    const int x0 = tid, x1 = tid + 360;
    const int t0 = (x0 * k0) % NX;
    const int t1 = (x1 * k0) % NX;
    float c0 = tw[t0].x, s0 = tw[t0].y;
    float c1 = tw[t1].x, s1 = tw[t1].y;
    const float dc0 = tw[x0].x, dn0 = tw[x0].y;
    const float dc1 = tw[x1].x, dn1 = tw[x1].y;
    float a0 = 0.f, a1 = 0.f;
    for (int kk = 0; kk < nk; ++kk) {
      const int k = k0 + kk;
      const float w = (k==0 || k==360) ? 1.0f : 2.0f;
      a0 = fmaf(sc[kk], w*c0, fmaf(ss[kk], w*s0, a0));
      a1 = fmaf(sc[kk], w*c1, fmaf(ss[kk], w*s1, a1));
      float n0 = c0*dc0 - s0*dn0; s0 = c0*dn0 + s0*dc0; c0 = n0;
      float n1 = c1*dc1 - s1*dn1; s1 = c1*dn1 + s1*dc1; c1 = n1;
    }
    const float inv = 1.0f/720.0f;
    float o0 = keepmode ? a0*inv : f[x0] - a0*inv;
    float o1 = keepmode ? a1*inv : f[x1] - a1*inv;
    o0 = fminf(fmaxf(o0, -0.5f), 0.5f);
    o1 = fminf(fmaxf(o1, -0.5f), 0.5f);
    base[x0] = o0;
    base[x1] = o1;
  }
}

// -------------------- host --------------------
extern "C" void kernel_launch(void* const* d_in, const int* in_sizes, int n_in,
                              void* d_out, int out_size, void* d_ws, size_t ws_size,
                              hipStream_t stream) {
  (void)in_sizes; (void)n_in; (void)d_ws; (void)ws_size; (void)out_size;
  const float* u  = (const float*)d_in[0];
  const float* v  = (const float*)d_in[1];
  const float* T  = (const float*)d_in[2];
  const float* ps = (const float*)d_in[4];
  const float* Rp = (const float*)d_in[6];

  float* out = (float*)d_out;
  float* du  = out;
  float* dv  = out + (size_t)NPTS;
  float* dT  = out + (size_t)2*NPTS;
  float* dq  = out + (size_t)3*NPTS;   // staged as div_h scratch, zeroed below
  float* dps = out + (size_t)4*NPTS;

  k_divh<<<NPTS/256, 256, 0, stream>>>(u, v, dq);
  k_tend<<<NCOL/8,   256, 0, stream>>>(u, v, T, ps, Rp, dq, du, dv, dT, dps);
  k_zero<<<NPTS/(256*4), 256, 0, stream>>>((float4*)dq);
  k_filter4b<<<3*NB*NY*4, 384, 0, stream>>>(du, dv, dT);
  k_filter_ps<<<NB*NY, 384, 0, stream>>>(dps);
}

// Round 8
// 595.417 us; speedup vs baseline: 1.1856x; 1.0831x over previous
//
#include <hip/hip_runtime.h>
#include <math.h>

#define NB 2
#define NY 360
#define NX 720
#define NZ 32
#define NPTS (NB*NY*NX*NZ)     // 16,588,800
#define NCOL (NB*NY*NX)        // 518,400

__device__ __forceinline__ int i4(int b,int y,int x,int z){ return (((b*NY)+y)*NX+x)*NZ+z; }
__device__ __forceinline__ int i3(int b,int y,int x){ return ((b*NY)+y)*NX+x; }

#define F_RAD   6371000.0f
#define F_OMEGA 7.292e-5f
#define F_CP    1004.0f
#define F_DLAT  ((float)(M_PI/360.0))                 /* == dlon */
#define F_DYR   ((float)(M_PI/360.0*6371000.0))      /* dlat*RAD */
#define F_HPI   ((float)(M_PI/2.0))
#define TH      ((float)(2.0*M_PI/720.0))

// -------------------- kernel 1: div_h = du/dx + dv/dy --------------------
__global__ __launch_bounds__(256) void k_divh(const float* __restrict__ u,
                                              const float* __restrict__ v,
                                              float* __restrict__ divh) {
  int gid = blockIdx.x*256 + threadIdx.x;          // exact: 64800*256 = NPTS
  int z  = gid & 31;
  int x  = (gid >> 5) % NX;
  int by = gid / (NX*NZ);
  int y  = by % NY;
  int b  = by / NY;
  float lat = -F_HPI + (y+0.5f)*F_DLAT;
  float cl  = cosf(lat);
  float invdx = 0.5f/(F_DLAT*F_RAD*cl);
  int xp = (x==NX-1)?0:x+1, xm = (x==0)?NX-1:x-1;
  float dudx = (u[i4(b,y,xp,z)] - u[i4(b,y,xm,z)]) * invdx;
  float dvdy;
  if (y == 0)          dvdy = (v[i4(b,1,x,z)]    - v[i4(b,0,x,z)])    * (1.0f/F_DYR);
  else if (y == NY-1)  dvdy = (v[i4(b,NY-1,x,z)] - v[i4(b,NY-2,x,z)]) * (1.0f/F_DYR);
  else                 dvdy = (v[i4(b,y+1,x,z)]  - v[i4(b,y-1,x,z)])  * (0.5f/F_DYR);
  divh[gid] = dudx + dvdy;
}

// -------------------- kernel 2: all raw tendencies --------------------
__global__ __launch_bounds__(256) void k_tend(
    const float* __restrict__ u, const float* __restrict__ v,
    const float* __restrict__ T, const float* __restrict__ ps,
    const float* __restrict__ Rp, const float* __restrict__ divh,
    float* __restrict__ du, float* __restrict__ dv,
    float* __restrict__ dT, float* __restrict__ dps) {
  const int tid = threadIdx.x;
  const int z   = tid & 31;
  const int col = blockIdx.x*8 + (tid>>5);         // exact: 64800*8 = NCOL
  const int x = col % NX;
  const int y = (col / NX) % NY;
  const int b = col / (NX*NY);
  const float R = Rp[0];

  const int xp = (x==NX-1)?0:x+1, xm = (x==0)?NX-1:x-1;
  const int ycm = (y>0)? y-1 : 0;
  const int ycp = (y<NY-1)? y+1 : NY-1;
  const bool y0 = (y==0), yN = (y==NY-1);

  const float lat  = -F_HPI + (y+0.5f)*F_DLAT;
  const float cl   = cosf(lat);
  const float fcor = 2.0f*F_OMEGA*sinf(lat);
  const float sx     = F_DLAT*F_RAD*cl;
  const float invdx  = 0.5f/sx;
  const float inv2dy = 0.5f/F_DYR;
  const float inv1dy = 1.0f/F_DYR;
  const float invsx2 = 1.0f/(sx*sx);
  const float invsy2 = 1.0f/(F_DYR*F_DYR);
  const float bk  = (z + 0.5f)/32.0f;
  const float dsv = 1.0f/32.0f;

  const int ic  = i4(b,y,x,z),   ixp = i4(b,y,xp,z), ixm = i4(b,y,xm,z);
  const int iyp = i4(b,ycp,x,z), iym = i4(b,ycm,x,z);

  const float uc=u[ic], uxp=u[ixp], uxm=u[ixm], uyp=u[iyp], uym=u[iym];
  const float vc=v[ic], vxp=v[ixp], vxm=v[ixm], vyp=v[iyp], vym=v[iym];
  const float Tc=T[ic], Txp=T[ixp], Txm=T[ixm], Typ=T[iyp], Tym=T[iym];
  const float Dc=divh[ic], Dxp=divh[ixp], Dxm=divh[ixm], Dyp=divh[iyp], Dym=divh[iym];
  const float psc=ps[i3(b,y,x)],   psxp=ps[i3(b,y,xp)], psxm=ps[i3(b,y,xm)];
  const float psyp=ps[i3(b,ycp,x)], psym=ps[i3(b,ycm,x)];

  auto dfy = [&](float fc_, float fyp_, float fym_) -> float {
    if (y0) return (fyp_ - fc_) * inv1dy;
    if (yN) return (fc_ - fym_) * inv1dy;
    return (fyp_ - fym_) * inv2dy;
  };
  auto lap = [&](float fc_, float fxp_, float fxm_, float fyp_, float fym_) -> float {
    float d2x = (fxp_ + fxm_ - 2.0f*fc_) * invsx2;
    float d2y = (y0||yN) ? 0.0f : (fyp_ + fym_ - 2.0f*fc_) * invsy2;
    return d2x + d2y;
  };
  auto sufscan = [&](float vv) -> float {   // vv[z] = sum_{j>=z}
    #pragma unroll
    for (int d=1; d<32; d<<=1) { float t = __shfl_down(vv, d, 32); if (z+d<32) vv += t; }
    return vv;
  };
  auto prescan = [&](float vv) -> float {   // vv[z] = sum_{j<=z}
    #pragma unroll
    for (int d=1; d<32; d<<=1) { float t = __shfl_up(vv, d, 32); if (z>=d) vv += t; }
    return vv;
  };
  auto vg = [&](float fc_) -> float {       // d/dsigma
    float fzp = __shfl_down(fc_,1,32), fzm = __shfl_up(fc_,1,32);
    if (z==0)  return (fzp - fc_) * 32.0f;
    if (z==31) return (fc_ - fzm) * 32.0f;
    return (fzp - fzm) * 16.0f;
  };

  const float rz = dsv / bk;
  const float phic  = sufscan(R*Tc*rz);
  const float phixp = sufscan(R*Txp*rz);
  const float phixm = sufscan(R*Txm*rz);
  const float phiyp = sufscan(R*Typ*rz);
  const float phiym = sufscan(R*Tym*rz);

  const float dudx = (uxp-uxm)*invdx, dvdx = (vxp-vxm)*invdx, dTdx = (Txp-Txm)*invdx;
  const float dphidx = (phixp-phixm)*invdx;
  const float dudy = dfy(uc,uyp,uym), dvdy_ = dfy(vc,vyp,vym), dTdy = dfy(Tc,Typ,Tym);
  const float dphidy = dfy(phic,phiyp,phiym);
  const float dpsdx = (psxp-psxm)*invdx, dpsdy = dfy(psc,psyp,psym);
  const float gdivx = (Dxp-Dxm)*invdx,  gdivy = dfy(Dc,Dyp,Dym);

  const float mass = Dc*psc + uc*dpsdx + vc*dpsdy;
  float Ipre = prescan(mass) * dsv;
  const float Itot = __shfl(Ipre, 31, 32);
  const float sigd = (bk*Itot - Ipre) / (psc + 1e-8f);

  const float vgu = vg(uc), vgv = vg(vc), vgT = vg(Tc);

  const float pfac = R*Tc*bk/(bk*psc + 1e-8f);
  const float pgfu = -dphidx - pfac*dpsdx;
  const float pgfv = -dphidy - pfac*dpsdy;
  const float cf2  = fmaxf(cl*cl, 0.01f);
  const float nudiv = 500000.0f*cf2, nuh = 100000.0f*cf2;
  const float lapu = lap(uc,uxp,uxm,uyp,uym);
  const float lapv = lap(vc,vxp,vxm,vyp,vym);
  const float lapT = lap(Tc,Txp,Txm,Typ,Tym);
  const float adiab = R*Tc/(bk*psc*F_CP + 1e-8f) * (sigd*psc);

  float dut = -(uc*dudx + vc*dudy)  - sigd*vgu + fcor*vc + pgfu + nuh*lapu - 1e-5f*uc + nudiv*gdivx;
  float dvt = -(uc*dvdx + vc*dvdy_) - sigd*vgv - fcor*uc + pgfv + nuh*lapv - 1e-5f*vc + nudiv*gdivy;
  float dTt = -(uc*dTdx + vc*dTdy)  - sigd*vgT + adiab + nuh*lapT;

  du[ic] = dut; dv[ic] = dvt; dT[ic] = dTt;
  if (z == 0) dps[i3(b,y,x)] = -Itot;
}

// -------------------- polar filter helpers --------------------
__device__ __forceinline__ void filter_band(int y, int& k0, int& k1, bool& keepmode) {
  float lat = -F_HPI + (y+0.5f)*F_DLAT;
  float cut = fmaxf(360.0f*cosf(lat), 1.0f);
  int M = (int)floorf(cut);
  keepmode = (M <= 179);
  k0 = keepmode ? 0 : (M+1);
  k1 = keepmode ? M : 360;
}

// -------------------- kernel 3: folded-DFT polar filter, all outputs ------
// Grid 9360 = 8640 field blocks + 720 dpsdt blocks (block-uniform branch,
// overlaid smem). Field blocks also zero their dq slice (k_zero fused).
// Analysis thread = (ks 0..95, xq 0..3): one k x 8 z per thread, 45-x chain
// (rot overhead per FMA halved vs 4z). Dual mode (cnt>48): xq pairs take
// k, k+96 over 90-x halves. Combine via shfl_xor in the 4-lane group.
#define FKMAX 180
__global__ __launch_bounds__(384) void k_filter4b(
    float* __restrict__ du, float* __restrict__ dv, float* __restrict__ dT,
    float* __restrict__ dps, float* __restrict__ dq) {
  __shared__ __align__(16) float smem[8640];   // 34.56 KB

  const int tid = threadIdx.x;
  // bijective XCD-chunk swizzle: 9360 = 8 * 1170
  const int bid = (blockIdx.x & 7) * 1170 + (blockIdx.x >> 3);

  if (bid >= 8640) {
    // ---------------- dpsdt filter path (720 blocks) ----------------
    float*  f  = smem;                          // [720]
    float2* tw = (float2*)(smem + 720);         // [720]
    float*  sc = smem + 720 + 1440;             // [184]
    float*  ss = sc + 184;
    const int row = bid - 8640;                 // 0..719 = b*360+y
    const int y = row % NY;
    float* base = dps + (size_t)row*NX;
    for (int t = tid; t < NX; t += 384) {
      float a = (float)t * TH;
      float sv, cv; sincosf(a, &sv, &cv);
      tw[t] = make_float2(cv, sv);
      f[t] = base[t];
    }
    int k0, k1; bool keepmode;
    filter_band(y, k0, k1, keepmode);
    const int nk = k1 - k0 + 1;
    __syncthreads();
    if (tid < nk) {
      const int k = k0 + tid;
      float ac=0.f, as=0.f; int idx=0;
      for (int xx=0; xx<NX; ++xx) {
        const float fv = f[xx];
        const float2 t2 = tw[idx];
        ac = fmaf(fv, t2.x, ac); as = fmaf(fv, t2.y, as);
        idx += k; if (idx >= NX) idx -= NX;
      }
      sc[tid]=ac; ss[tid]=as;
    }
    __syncthreads();
    if (tid < 360) {
      const int x0 = tid, x1 = tid + 360;
      const int t0 = (x0 * k0) % NX;
      const int t1 = (x1 * k0) % NX;
      float c0 = tw[t0].x, s0 = tw[t0].y;
      float c1 = tw[t1].x, s1 = tw[t1].y;
      const float dc0 = tw[x0].x, dn0 = tw[x0].y;
      const float dc1 = tw[x1].x, dn1 = tw[x1].y;
      float a0 = 0.f, a1 = 0.f;
      for (int kk = 0; kk < nk; ++kk) {
        const int k = k0 + kk;
        const float w = (k==0 || k==360) ? 1.0f : 2.0f;
        a0 = fmaf(sc[kk], w*c0, fmaf(ss[kk], w*s0, a0));
        a1 = fmaf(sc[kk], w*c1, fmaf(ss[kk], w*s1, a1));
        float n0 = c0*dc0 - s0*dn0; s0 = c0*dn0 + s0*dc0; c0 = n0;
        float n1 = c1*dc1 - s1*dn1; s1 = c1*dn1 + s1*dc1; c1 = n1;
      }
      const float inv = 1.0f/720.0f;
      float o0 = keepmode ? a0*inv : f[x0] - a0*inv;
      float o1 = keepmode ? a1*inv : f[x1] - a1*inv;
      o0 = fminf(fmaxf(o0, -0.5f), 0.5f);
      o1 = fminf(fmaxf(o1, -0.5f), 0.5f);
      base[x0] = o0;
      base[x1] = o1;
    }
    return;
  }

  // ---------------- field filter path (8640 blocks) ----------------
  float (*S0)[8]    = (float(*)[8])   smem;           // [180][8]
  float (*S2)[8]    = (float(*)[8])  (smem + 1440);   // [180][8]
  float (*AB)[8][2] = (float(*)[8][2])(smem + 2880);  // [180][8][2]
  float (*SD)[8][2] = (float(*)[8][2])(smem + 5760);  // [180][8][2]

  // fused k_zero: each field block zeroes its 1920-float dq slice
  {
    float4* dqv = (float4*)dq + (size_t)bid * 480;
    const float4 z4 = make_float4(0.f,0.f,0.f,0.f);
    for (int t = tid; t < 480; t += 384) dqv[t] = z4;
  }

  const int zq   = bid & 3;
  const int rest = bid >> 2;
  const int by   = rest % (NB*NY);
  const int fld  = rest / (NB*NY);
  const int y = by % NY, b = by / NY;
  float* fptr = (fld==0)? du : (fld==1)? dv : dT;
  const float clipv = (fld==2)? 0.01f : 0.02f;
  float* base = fptr + ((size_t)(b*NY+y)*NX)*NZ + zq*8;

  int k0, k1; bool keep;
  filter_band(y, k0, k1, keep);

  // ---- load + fold ----
  if (tid < 360) {
    const int x  = tid % 180;
    const int zh = tid / 180;                       // 0/1 -> z offset 4*zh
    const float4 q0 = *(const float4*)(base + (size_t)(x      )*NZ + zh*4);
    const float4 q1 = *(const float4*)(base + (size_t)(x + 180)*NZ + zh*4);
    const float4 q2 = *(const float4*)(base + (size_t)(x + 360)*NZ + zh*4);
    const float4 q3 = *(const float4*)(base + (size_t)(x + 540)*NZ + zh*4);
    float4 s0v, s2v, av, bv;
    s0v.x=q0.x+q1.x+q2.x+q3.x; s2v.x=q0.x-q1.x+q2.x-q3.x; av.x=q0.x-q2.x; bv.x=q1.x-q3.x;
    s0v.y=q0.y+q1.y+q2.y+q3.y; s2v.y=q0.y-q1.y+q2.y-q3.y; av.y=q0.y-q2.y; bv.y=q1.y-q3.y;
    s0v.z=q0.z+q1.z+q2.z+q3.z; s2v.z=q0.z-q1.z+q2.z-q3.z; av.z=q0.z-q2.z; bv.z=q1.z-q3.z;
    s0v.w=q0.w+q1.w+q2.w+q3.w; s2v.w=q0.w-q1.w+q2.w-q3.w; av.w=q0.w-q2.w; bv.w=q1.w-q3.w;
    *(float4*)&S0[x][zh*4] = s0v;
    *(float4*)&S2[x][zh*4] = s2v;
    *(float4*)&AB[x][zh*4+0][0] = make_float4(av.x, bv.x, av.y, bv.y);
    *(float4*)&AB[x][zh*4+2][0] = make_float4(av.z, bv.z, av.w, bv.w);
  }
  __syncthreads();

  // ---- analysis: thread = (ks 0..95, xq 0..3); one k, 8 z ----
  {
    const int xq = tid & 3;
    const int ks = tid >> 2;            // 0..95; waves 0-2 even-class, 3-5 odd
    const bool isodd = (ks >= 48);
    const int slot = isodd ? ks - 48 : ks;
    const int ke0 = k0 + (k0 & 1);      // first even >= k0
    const int ko0 = k0 | 1;             // first odd  >= k0
    const int kbase = isodd ? ko0 : ke0;
    const int cnt   = (k1 >= kbase) ? (((k1 - kbase) >> 1) + 1) : 0;
    const bool dual = (cnt > 48);
    int k, x0, xe; bool act;
    if (dual) { k = kbase + 2*(slot + 48*(xq>>1)); x0 = 90*(xq&1); xe = x0+90; act = (k <= k1); }
    else      { k = kbase + 2*slot;                x0 = 45*xq;     xe = x0+45; act = (slot < cnt); }

    float ac[8], as[8];
    #pragma unroll
    for (int j=0;j<8;++j){ ac[j]=0.f; as[j]=0.f; }

    if (act) {
      float dc, ds; sincosf((float)k * TH, &ds, &dc);
      float c, s;   sincosf((float)((k * x0) % 720) * TH, &s, &c);
      if (!isodd) {
        const float* Sp = ((k & 3) == 0) ? &S0[0][0] : &S2[0][0];
        for (int x = x0; x < xe; ++x) {
          const float4 a  = *(const float4*)&Sp[x*8];
          const float4 b4 = *(const float4*)&Sp[x*8+4];
          ac[0]=fmaf(a.x ,c,ac[0]); as[0]=fmaf(a.x ,s,as[0]);
          ac[1]=fmaf(a.y ,c,ac[1]); as[1]=fmaf(a.y ,s,as[1]);
          ac[2]=fmaf(a.z ,c,ac[2]); as[2]=fmaf(a.z ,s,as[2]);
          ac[3]=fmaf(a.w ,c,ac[3]); as[3]=fmaf(a.w ,s,as[3]);
          ac[4]=fmaf(b4.x,c,ac[4]); as[4]=fmaf(b4.x,s,as[4]);
          ac[5]=fmaf(b4.y,c,ac[5]); as[5]=fmaf(b4.y,s,as[5]);
          ac[6]=fmaf(b4.z,c,ac[6]); as[6]=fmaf(b4.z,s,as[6]);
          ac[7]=fmaf(b4.w,c,ac[7]); as[7]=fmaf(b4.w,s,as[7]);
          const float nc = fmaf(c, dc, -s*ds);
          s = fmaf(s, dc, c*ds); c = nc;
        }
      } else {
        const float sg = ((k & 3) == 1) ? 1.0f : -1.0f;
        for (int x = x0; x < xe; ++x) {
          const float4 p0 = *(const float4*)&AB[x][0][0]; // A0,B0,A1,B1
          const float4 p1 = *(const float4*)&AB[x][2][0]; // A2,B2,A3,B3
          const float4 p2 = *(const float4*)&AB[x][4][0]; // A4,B4,A5,B5
          const float4 p3 = *(const float4*)&AB[x][6][0]; // A6,B6,A7,B7
          const float sgc = sg*c, sgs = sg*s;
          ac[0]=fmaf(p0.x,c,fmaf(p0.y,-sgs,ac[0])); as[0]=fmaf(p0.x,s,fmaf(p0.y,sgc,as[0]));
          ac[1]=fmaf(p0.z,c,fmaf(p0.w,-sgs,ac[1])); as[1]=fmaf(p0.z,s,fmaf(p0.w,sgc,as[1]));
          ac[2]=fmaf(p1.x,c,fmaf(p1.y,-sgs,ac[2])); as[2]=fmaf(p1.x,s,fmaf(p1.y,sgc,as[2]));
          ac[3]=fmaf(p1.z,c,fmaf(p1.w,-sgs,ac[3])); as[3]=fmaf(p1.z,s,fmaf(p1.w,sgc,as[3]));
          ac[4]=fmaf(p2.x,c,fmaf(p2.y,-sgs,ac[4])); as[4]=fmaf(p2.x,s,fmaf(p2.y,sgc,as[4]));
          ac[5]=fmaf(p2.z,c,fmaf(p2.w,-sgs,ac[5])); as[5]=fmaf(p2.z,s,fmaf(p2.w,sgc,as[5]));
          ac[6]=fmaf(p3.x,c,fmaf(p3.y,-sgs,ac[6])); as[6]=fmaf(p3.x,s,fmaf(p3.y,sgc,as[6]));
          ac[7]=fmaf(p3.z,c,fmaf(p3.w,-sgs,ac[7])); as[7]=fmaf(p3.z,s,fmaf(p3.w,sgc,as[7]));
          const float nc = fmaf(c, dc, -s*ds);
          s = fmaf(s, dc, c*ds); c = nc;
        }
      }
    }
    // combine partial sums over the 4-lane xq group
    #pragma unroll
    for (int j=0;j<8;++j){
      ac[j] += __shfl_xor(ac[j], 1);
      as[j] += __shfl_xor(as[j], 1);
    }
    if (!dual) {
      #pragma unroll
      for (int j=0;j<8;++j){
        ac[j] += __shfl_xor(ac[j], 2);
        as[j] += __shfl_xor(as[j], 2);
      }
    }
    if (act && ((xq & (dual ? 1 : 3)) == 0)) {
      const float w = (k==0 || k==360) ? 1.0f : 2.0f;
      const int r = k - k0;
      *(float4*)&SD[r][0][0] = make_float4(w*ac[0], w*as[0], w*ac[1], w*as[1]);
      *(float4*)&SD[r][2][0] = make_float4(w*ac[2], w*as[2], w*ac[3], w*as[3]);
      *(float4*)&SD[r][4][0] = make_float4(w*ac[4], w*as[4], w*ac[5], w*as[5]);
      *(float4*)&SD[r][6][0] = make_float4(w*ac[6], w*as[6], w*ac[7], w*as[7]);
    }
  }
  __syncthreads();

  // ---- synthesis: thread = (x' 0..179, z-half 0..1), 4 z each ----
  if (tid < 360) {
    const int x  = tid % 180;
    const int zh = tid / 180;
    float HreE[2][4]; float Hro[2][4]; float Hio[2][4];
    #pragma unroll
    for (int i = 0; i < 2; ++i)
      #pragma unroll
      for (int j = 0; j < 4; ++j) { HreE[i][j]=0.f; Hro[i][j]=0.f; Hio[i][j]=0.f; }

    const int m4 = (4*x) % 720;
    float dstep_s, dstep_c; sincosf((float)m4 * TH, &dstep_s, &dstep_c);

    // even residues r=0,2: only Re needed
    #pragma unroll
    for (int ri = 0; ri < 2; ++ri) {
      const int r = ri*2;
      const int kst = k0 + ((r - (k0 & 3) + 4) & 3);
      if (kst > k1) continue;
      int mm = (kst * x) % 720;
      float sv, cv; sincosf((float)mm * TH, &sv, &cv);
      for (int k = kst; k <= k1; k += 4) {
        const float4 d01 = *(const float4*)&SD[k - k0][zh*4 + 0][0];
        const float4 d23 = *(const float4*)&SD[k - k0][zh*4 + 2][0];
        HreE[ri][0] = fmaf(d01.x, cv, fmaf(d01.y, sv, HreE[ri][0]));
        HreE[ri][1] = fmaf(d01.z, cv, fmaf(d01.w, sv, HreE[ri][1]));
        HreE[ri][2] = fmaf(d23.x, cv, fmaf(d23.y, sv, HreE[ri][2]));
        HreE[ri][3] = fmaf(d23.z, cv, fmaf(d23.w, sv, HreE[ri][3]));
        float nc = fmaf(cv, dstep_c, -sv*dstep_s);   // forward rotation +4x*theta
        float ns = fmaf(sv, dstep_c,  cv*dstep_s);
        cv = nc; sv = ns;
      }
    }
    // odd residues r=1,3: Re and Im
    #pragma unroll
    for (int ri = 0; ri < 2; ++ri) {
      const int r = ri*2 + 1;
      const int kst = k0 + ((r - (k0 & 3) + 4) & 3);
      if (kst > k1) continue;
      int mm = (kst * x) % 720;
      float sv, cv; sincosf((float)mm * TH, &sv, &cv);
      for (int k = kst; k <= k1; k += 4) {
        const float4 d01 = *(const float4*)&SD[k - k0][zh*4 + 0][0];
        const float4 d23 = *(const float4*)&SD[k - k0][zh*4 + 2][0];
        Hro[ri][0] = fmaf(d01.x, cv, fmaf(d01.y, sv, Hro[ri][0]));
        Hio[ri][0] = fmaf(d01.y, cv, fmaf(-d01.x, sv, Hio[ri][0]));
        Hro[ri][1] = fmaf(d01.z, cv, fmaf(d01.w, sv, Hro[ri][1]));
        Hio[ri][1] = fmaf(d01.w, cv, fmaf(-d01.z, sv, Hio[ri][1]));
        Hro[ri][2] = fmaf(d23.x, cv, fmaf(d23.y, sv, Hro[ri][2]));
        Hio[ri][2] = fmaf(d23.y, cv, fmaf(-d23.x, sv, Hio[ri][2]));
        Hro[ri][3] = fmaf(d23.z, cv, fmaf(d23.w, sv, Hro[ri][3]));
        Hio[ri][3] = fmaf(d23.w, cv, fmaf(-d23.z, sv, Hio[ri][3]));
        float nc = fmaf(cv, dstep_c, -sv*dstep_s);   // forward rotation +4x*theta
        float ns = fmaf(sv, dstep_c,  cv*dstep_s);
        cv = nc; sv = ns;
      }
    }

    const float inv = 1.0f/720.0f;
    float o[4][4];
    float4 s0v, s2v, ab01, ab23;
    if (!keep) {
      s0v  = *(const float4*)&S0[x][zh*4];
      s2v  = *(const float4*)&S2[x][zh*4];
      ab01 = *(const float4*)&AB[x][zh*4+0][0];
      ab23 = *(const float4*)&AB[x][zh*4+2][0];
    }
    #pragma unroll
    for (int j = 0; j < 4; ++j) {
      const float h0  = HreE[0][j], h2 = HreE[1][j];
      const float h1r = Hro[0][j],  h1i = Hio[0][j];
      const float h3r = Hro[1][j],  h3i = Hio[1][j];
      float l0 = (h0 + h1r + h2 + h3r) * inv;
      float l1 = (h0 + h1i - h2 - h3i) * inv;
      float l2 = (h0 - h1r + h2 - h3r) * inv;
      float l3 = (h0 - h1i - h2 + h3i) * inv;
      if (!keep) {
        const float s0j = (j==0)?s0v.x:(j==1)?s0v.y:(j==2)?s0v.z:s0v.w;
        const float s2j = (j==0)?s2v.x:(j==1)?s2v.y:(j==2)?s2v.z:s2v.w;
        const float aj  = (j==0)?ab01.x:(j==1)?ab01.z:(j==2)?ab23.x:ab23.z;
        const float bj  = (j==0)?ab01.y:(j==1)?ab01.w:(j==2)?ab23.y:ab23.w;
        const float sp = 0.25f*(s0j + s2j), sm = 0.25f*(s0j - s2j);
        const float q0v = sp + 0.5f*aj, q2v = sp - 0.5f*aj;
        const float q1v = sm + 0.5f*bj, q3v = sm - 0.5f*bj;
        l0 = q0v - l0; l1 = q1v - l1; l2 = q2v - l2; l3 = q3v - l3;
      }
      o[0][j] = fminf(fmaxf(l0, -clipv), clipv);
      o[1][j] = fminf(fmaxf(l1, -clipv), clipv);
      o[2][j] = fminf(fmaxf(l2, -clipv), clipv);
      o[3][j] = fminf(fmaxf(l3, -clipv), clipv);
    }
    #pragma unroll
    for (int j = 0; j < 4; ++j) {
      *(float4*)(base + (size_t)(x + 180*j)*NZ + zh*4) =
          make_float4(o[j][0], o[j][1], o[j][2], o[j][3]);
    }
  }
}

// -------------------- host --------------------
extern "C" void kernel_launch(void* const* d_in, const int* in_sizes, int n_in,
                              void* d_out, int out_size, void* d_ws, size_t ws_size,
                              hipStream_t stream) {
  (void)in_sizes; (void)n_in; (void)d_ws; (void)ws_size; (void)out_size;
  const float* u  = (const float*)d_in[0];
  const float* v  = (const float*)d_in[1];
  const float* T  = (const float*)d_in[2];
  const float* ps = (const float*)d_in[4];
  const float* Rp = (const float*)d_in[6];

  float* out = (float*)d_out;
  float* du  = out;
  float* dv  = out + (size_t)NPTS;
  float* dT  = out + (size_t)2*NPTS;
  float* dq  = out + (size_t)3*NPTS;   // staged as div_h scratch; zeroed in filter
  float* dps = out + (size_t)4*NPTS;

  k_divh<<<NPTS/256, 256, 0, stream>>>(u, v, dq);
  k_tend<<<NCOL/8,   256, 0, stream>>>(u, v, T, ps, Rp, dq, du, dv, dT, dps);
  k_filter4b<<<9360, 384, 0, stream>>>(du, dv, dT, dps, dq);
}

// Round 9
// 575.303 us; speedup vs baseline: 1.2271x; 1.0350x over previous
//
#include <hip/hip_runtime.h>
#include <math.h>

#define NB 2
#define NY 360
#define NX 720
#define NZ 32
#define NPTS (NB*NY*NX*NZ)     // 16,588,800
#define NCOL (NB*NY*NX)        // 518,400

__device__ __forceinline__ int i4(int b,int y,int x,int z){ return (((b*NY)+y)*NX+x)*NZ+z; }
__device__ __forceinline__ int i3(int b,int y,int x){ return ((b*NY)+y)*NX+x; }

#define F_RAD   6371000.0f
#define F_OMEGA 7.292e-5f
#define F_CP    1004.0f
#define F_DLAT  ((float)(M_PI/360.0))                 /* == dlon */
#define F_DYR   ((float)(M_PI/360.0*6371000.0))      /* dlat*RAD */
#define F_HPI   ((float)(M_PI/2.0))
#define TH      ((float)(2.0*M_PI/720.0))

// -------------------- kernel 1: div_h = du/dx + dv/dy --------------------
__global__ __launch_bounds__(256) void k_divh(const float* __restrict__ u,
                                              const float* __restrict__ v,
                                              float* __restrict__ divh) {
  int gid = blockIdx.x*256 + threadIdx.x;          // exact: 64800*256 = NPTS
  int z  = gid & 31;
  int x  = (gid >> 5) % NX;
  int by = gid / (NX*NZ);
  int y  = by % NY;
  int b  = by / NY;
  float lat = -F_HPI + (y+0.5f)*F_DLAT;
  float cl  = cosf(lat);
  float invdx = 0.5f/(F_DLAT*F_RAD*cl);
  int xp = (x==NX-1)?0:x+1, xm = (x==0)?NX-1:x-1;
  float dudx = (u[i4(b,y,xp,z)] - u[i4(b,y,xm,z)]) * invdx;
  float dvdy;
  if (y == 0)          dvdy = (v[i4(b,1,x,z)]    - v[i4(b,0,x,z)])    * (1.0f/F_DYR);
  else if (y == NY-1)  dvdy = (v[i4(b,NY-1,x,z)] - v[i4(b,NY-2,x,z)]) * (1.0f/F_DYR);
  else                 dvdy = (v[i4(b,y+1,x,z)]  - v[i4(b,y-1,x,z)])  * (0.5f/F_DYR);
  divh[gid] = dudx + dvdy;
}

// -------------------- kernel 2: all raw tendencies --------------------
__global__ __launch_bounds__(256) void k_tend(
    const float* __restrict__ u, const float* __restrict__ v,
    const float* __restrict__ T, const float* __restrict__ ps,
    const float* __restrict__ Rp, const float* __restrict__ divh,
    float* __restrict__ du, float* __restrict__ dv,
    float* __restrict__ dT, float* __restrict__ dps) {
  const int tid = threadIdx.x;
  const int z   = tid & 31;
  const int col = blockIdx.x*8 + (tid>>5);         // exact: 64800*8 = NCOL
  const int x = col % NX;
  const int y = (col / NX) % NY;
  const int b = col / (NX*NY);
  const float R = Rp[0];

  const int xp = (x==NX-1)?0:x+1, xm = (x==0)?NX-1:x-1;
  const int ycm = (y>0)? y-1 : 0;
  const int ycp = (y<NY-1)? y+1 : NY-1;
  const bool y0 = (y==0), yN = (y==NY-1);

  const float lat  = -F_HPI + (y+0.5f)*F_DLAT;
  const float cl   = cosf(lat);
  const float fcor = 2.0f*F_OMEGA*sinf(lat);
  const float sx     = F_DLAT*F_RAD*cl;
  const float invdx  = 0.5f/sx;
  const float inv2dy = 0.5f/F_DYR;
  const float inv1dy = 1.0f/F_DYR;
  const float invsx2 = 1.0f/(sx*sx);
  const float invsy2 = 1.0f/(F_DYR*F_DYR);
  const float bk  = (z + 0.5f)/32.0f;
  const float dsv = 1.0f/32.0f;

  const int ic  = i4(b,y,x,z),   ixp = i4(b,y,xp,z), ixm = i4(b,y,xm,z);
  const int iyp = i4(b,ycp,x,z), iym = i4(b,ycm,x,z);

  const float uc=u[ic], uxp=u[ixp], uxm=u[ixm], uyp=u[iyp], uym=u[iym];
  const float vc=v[ic], vxp=v[ixp], vxm=v[ixm], vyp=v[iyp], vym=v[iym];
  const float Tc=T[ic], Txp=T[ixp], Txm=T[ixm], Typ=T[iyp], Tym=T[iym];
  const float Dc=divh[ic], Dxp=divh[ixp], Dxm=divh[ixm], Dyp=divh[iyp], Dym=divh[iym];
  const float psc=ps[i3(b,y,x)],   psxp=ps[i3(b,y,xp)], psxm=ps[i3(b,y,xm)];
  const float psyp=ps[i3(b,ycp,x)], psym=ps[i3(b,ycm,x)];

  auto dfy = [&](float fc_, float fyp_, float fym_) -> float {
    if (y0) return (fyp_ - fc_) * inv1dy;
    if (yN) return (fc_ - fym_) * inv1dy;
    return (fyp_ - fym_) * inv2dy;
  };
  auto lap = [&](float fc_, float fxp_, float fxm_, float fyp_, float fym_) -> float {
    float d2x = (fxp_ + fxm_ - 2.0f*fc_) * invsx2;
    float d2y = (y0||yN) ? 0.0f : (fyp_ + fym_ - 2.0f*fc_) * invsy2;
    return d2x + d2y;
  };
  auto sufscan = [&](float vv) -> float {   // vv[z] = sum_{j>=z}
    #pragma unroll
    for (int d=1; d<32; d<<=1) { float t = __shfl_down(vv, d, 32); if (z+d<32) vv += t; }
    return vv;
  };
  auto prescan = [&](float vv) -> float {   // vv[z] = sum_{j<=z}
    #pragma unroll
    for (int d=1; d<32; d<<=1) { float t = __shfl_up(vv, d, 32); if (z>=d) vv += t; }
    return vv;
  };
  auto vg = [&](float fc_) -> float {       // d/dsigma
    float fzp = __shfl_down(fc_,1,32), fzm = __shfl_up(fc_,1,32);
    if (z==0)  return (fzp - fc_) * 32.0f;
    if (z==31) return (fc_ - fzm) * 32.0f;
    return (fzp - fzm) * 16.0f;
  };

  const float rz = dsv / bk;
  const float phic  = sufscan(R*Tc*rz);
  const float phixp = sufscan(R*Txp*rz);
  const float phixm = sufscan(R*Txm*rz);
  const float phiyp = sufscan(R*Typ*rz);
  const float phiym = sufscan(R*Tym*rz);

  const float dudx = (uxp-uxm)*invdx, dvdx = (vxp-vxm)*invdx, dTdx = (Txp-Txm)*invdx;
  const float dphidx = (phixp-phixm)*invdx;
  const float dudy = dfy(uc,uyp,uym), dvdy_ = dfy(vc,vyp,vym), dTdy = dfy(Tc,Typ,Tym);
  const float dphidy = dfy(phic,phiyp,phiym);
  const float dpsdx = (psxp-psxm)*invdx, dpsdy = dfy(psc,psyp,psym);
  const float gdivx = (Dxp-Dxm)*invdx,  gdivy = dfy(Dc,Dyp,Dym);

  const float mass = Dc*psc + uc*dpsdx + vc*dpsdy;
  float Ipre = prescan(mass) * dsv;
  const float Itot = __shfl(Ipre, 31, 32);
  const float sigd = (bk*Itot - Ipre) / (psc + 1e-8f);

  const float vgu = vg(uc), vgv = vg(vc), vgT = vg(Tc);

  const float pfac = R*Tc*bk/(bk*psc + 1e-8f);
  const float pgfu = -dphidx - pfac*dpsdx;
  const float pgfv = -dphidy - pfac*dpsdy;
  const float cf2  = fmaxf(cl*cl, 0.01f);
  const float nudiv = 500000.0f*cf2, nuh = 100000.0f*cf2;
  const float lapu = lap(uc,uxp,uxm,uyp,uym);
  const float lapv = lap(vc,vxp,vxm,vyp,vym);
  const float lapT = lap(Tc,Txp,Txm,Typ,Tym);
  const float adiab = R*Tc/(bk*psc*F_CP + 1e-8f) * (sigd*psc);

  float dut = -(uc*dudx + vc*dudy)  - sigd*vgu + fcor*vc + pgfu + nuh*lapu - 1e-5f*uc + nudiv*gdivx;
  float dvt = -(uc*dvdx + vc*dvdy_) - sigd*vgv - fcor*uc + pgfv + nuh*lapv - 1e-5f*vc + nudiv*gdivy;
  float dTt = -(uc*dTdx + vc*dTdy)  - sigd*vgT + adiab + nuh*lapT;

  du[ic] = dut; dv[ic] = dvt; dT[ic] = dTt;
  if (z == 0) dps[i3(b,y,x)] = -Itot;
}

// -------------------- polar filter helpers --------------------
__device__ __forceinline__ void filter_band(int y, int& k0, int& k1, bool& keepmode) {
  float lat = -F_HPI + (y+0.5f)*F_DLAT;
  float cut = fmaxf(360.0f*cosf(lat), 1.0f);
  int M = (int)floorf(cut);
  keepmode = (M <= 179);
  k0 = keepmode ? 0 : (M+1);
  k1 = keepmode ? M : 360;
}

// analysis inner-loop steps (constant trip counts enable unroll + LDS
// load batching; arithmetic order per accumulator identical to R8)
#define EVEN_STEP { \
  const float4 a  = *(const float4*)(Sp + i*8); \
  const float4 b4 = *(const float4*)(Sp + i*8 + 4); \
  ac[0]=fmaf(a.x ,c,ac[0]); as[0]=fmaf(a.x ,s,as[0]); \
  ac[1]=fmaf(a.y ,c,ac[1]); as[1]=fmaf(a.y ,s,as[1]); \
  ac[2]=fmaf(a.z ,c,ac[2]); as[2]=fmaf(a.z ,s,as[2]); \
  ac[3]=fmaf(a.w ,c,ac[3]); as[3]=fmaf(a.w ,s,as[3]); \
  ac[4]=fmaf(b4.x,c,ac[4]); as[4]=fmaf(b4.x,s,as[4]); \
  ac[5]=fmaf(b4.y,c,ac[5]); as[5]=fmaf(b4.y,s,as[5]); \
  ac[6]=fmaf(b4.z,c,ac[6]); as[6]=fmaf(b4.z,s,as[6]); \
  ac[7]=fmaf(b4.w,c,ac[7]); as[7]=fmaf(b4.w,s,as[7]); \
  const float nc = fmaf(c, dc, -s*ds); \
  s = fmaf(s, dc, c*ds); c = nc; }

#define ODD_STEP { \
  const float4 p0 = *(const float4*)(Ap + i*16); \
  const float4 p1 = *(const float4*)(Ap + i*16 + 4); \
  const float4 p2 = *(const float4*)(Ap + i*16 + 8); \
  const float4 p3 = *(const float4*)(Ap + i*16 + 12); \
  const float sgc = sg*c, sgs = sg*s; \
  ac[0]=fmaf(p0.x,c,fmaf(p0.y,-sgs,ac[0])); as[0]=fmaf(p0.x,s,fmaf(p0.y,sgc,as[0])); \
  ac[1]=fmaf(p0.z,c,fmaf(p0.w,-sgs,ac[1])); as[1]=fmaf(p0.z,s,fmaf(p0.w,sgc,as[1])); \
  ac[2]=fmaf(p1.x,c,fmaf(p1.y,-sgs,ac[2])); as[2]=fmaf(p1.x,s,fmaf(p1.y,sgc,as[2])); \
  ac[3]=fmaf(p1.z,c,fmaf(p1.w,-sgs,ac[3])); as[3]=fmaf(p1.z,s,fmaf(p1.w,sgc,as[3])); \
  ac[4]=fmaf(p2.x,c,fmaf(p2.y,-sgs,ac[4])); as[4]=fmaf(p2.x,s,fmaf(p2.y,sgc,as[4])); \
  ac[5]=fmaf(p2.z,c,fmaf(p2.w,-sgs,ac[5])); as[5]=fmaf(p2.z,s,fmaf(p2.w,sgc,as[5])); \
  ac[6]=fmaf(p3.x,c,fmaf(p3.y,-sgs,ac[6])); as[6]=fmaf(p3.x,s,fmaf(p3.y,sgc,as[6])); \
  ac[7]=fmaf(p3.z,c,fmaf(p3.w,-sgs,ac[7])); as[7]=fmaf(p3.z,s,fmaf(p3.w,sgc,as[7])); \
  const float nc = fmaf(c, dc, -s*ds); \
  s = fmaf(s, dc, c*ds); c = nc; }

// -------------------- kernel 3: folded-DFT polar filter, all outputs ------
// Grid 9360 = 8640 field blocks + 720 dpsdt blocks. launch_bounds(384,4)
// gives the register allocator headroom (R8's VGPR=40 left no room to
// pipeline ds_read_b128 -> every LDS read stalled on lgkmcnt).
#define FKMAX 180
__global__ __launch_bounds__(384, 4) void k_filter4b(
    float* __restrict__ du, float* __restrict__ dv, float* __restrict__ dT,
    float* __restrict__ dps, float* __restrict__ dq) {
  __shared__ __align__(16) float smem[8640];   // 34.56 KB

  const int tid = threadIdx.x;
  // bijective XCD-chunk swizzle: 9360 = 8 * 1170
  const int bid = (blockIdx.x & 7) * 1170 + (blockIdx.x >> 3);

  if (bid >= 8640) {
    // ---------------- dpsdt filter path (720 blocks) ----------------
    float*  f  = smem;                          // [720]
    float2* tw = (float2*)(smem + 720);         // [720]
    float*  sc = smem + 720 + 1440;             // [184]
    float*  ss = sc + 184;
    const int row = bid - 8640;                 // 0..719 = b*360+y
    const int y = row % NY;
    float* base = dps + (size_t)row*NX;
    for (int t = tid; t < NX; t += 384) {
      float a = (float)t * TH;
      float sv, cv; sincosf(a, &sv, &cv);
      tw[t] = make_float2(cv, sv);
      f[t] = base[t];
    }
    int k0, k1; bool keepmode;
    filter_band(y, k0, k1, keepmode);
    const int nk = k1 - k0 + 1;
    __syncthreads();
    if (tid < nk) {
      const int k = k0 + tid;
      float ac=0.f, as=0.f; int idx=0;
      for (int xx=0; xx<NX; ++xx) {
        const float fv = f[xx];
        const float2 t2 = tw[idx];
        ac = fmaf(fv, t2.x, ac); as = fmaf(fv, t2.y, as);
        idx += k; if (idx >= NX) idx -= NX;
      }
      sc[tid]=ac; ss[tid]=as;
    }
    __syncthreads();
    if (tid < 360) {
      const int x0 = tid, x1 = tid + 360;
      const int t0 = (x0 * k0) % NX;
      const int t1 = (x1 * k0) % NX;
      float c0 = tw[t0].x, s0 = tw[t0].y;
      float c1 = tw[t1].x, s1 = tw[t1].y;
      const float dc0 = tw[x0].x, dn0 = tw[x0].y;
      const float dc1 = tw[x1].x, dn1 = tw[x1].y;
      float a0 = 0.f, a1 = 0.f;
      for (int kk = 0; kk < nk; ++kk) {
        const int k = k0 + kk;
        const float w = (k==0 || k==360) ? 1.0f : 2.0f;
        a0 = fmaf(sc[kk], w*c0, fmaf(ss[kk], w*s0, a0));
        a1 = fmaf(sc[kk], w*c1, fmaf(ss[kk], w*s1, a1));
        float n0 = c0*dc0 - s0*dn0; s0 = c0*dn0 + s0*dc0; c0 = n0;
        float n1 = c1*dc1 - s1*dn1; s1 = c1*dn1 + s1*dc1; c1 = n1;
      }
      const float inv = 1.0f/720.0f;
      float o0 = keepmode ? a0*inv : f[x0] - a0*inv;
      float o1 = keepmode ? a1*inv : f[x1] - a1*inv;
      o0 = fminf(fmaxf(o0, -0.5f), 0.5f);
      o1 = fminf(fmaxf(o1, -0.5f), 0.5f);
      base[x0] = o0;
      base[x1] = o1;
    }
    return;
  }

  // ---------------- field filter path (8640 blocks) ----------------
  float (*S0)[8]    = (float(*)[8])   smem;           // [180][8]
  float (*S2)[8]    = (float(*)[8])  (smem + 1440);   // [180][8]
  float (*AB)[8][2] = (float(*)[8][2])(smem + 2880);  // [180][8][2]
  float (*SD)[8][2] = (float(*)[8][2])(smem + 5760);  // [180][8][2]

  // fused k_zero: each field block zeroes its 1920-float dq slice
  {
    float4* dqv = (float4*)dq + (size_t)bid * 480;
    const float4 z4 = make_float4(0.f,0.f,0.f,0.f);
    for (int t = tid; t < 480; t += 384) dqv[t] = z4;
  }

  const int zq   = bid & 3;
  const int rest = bid >> 2;
  const int by   = rest % (NB*NY);
  const int fld  = rest / (NB*NY);
  const int y = by % NY, b = by / NY;
  float* fptr = (fld==0)? du : (fld==1)? dv : dT;
  const float clipv = (fld==2)? 0.01f : 0.02f;
  float* base = fptr + ((size_t)(b*NY+y)*NX)*NZ + zq*8;

  int k0, k1; bool keep;
  filter_band(y, k0, k1, keep);

  // ---- load + fold ----
  if (tid < 360) {
    const int x  = tid % 180;
    const int zh = tid / 180;                       // 0/1 -> z offset 4*zh
    const float4 q0 = *(const float4*)(base + (size_t)(x      )*NZ + zh*4);
    const float4 q1 = *(const float4*)(base + (size_t)(x + 180)*NZ + zh*4);
    const float4 q2 = *(const float4*)(base + (size_t)(x + 360)*NZ + zh*4);
    const float4 q3 = *(const float4*)(base + (size_t)(x + 540)*NZ + zh*4);
    float4 s0v, s2v, av, bv;
    s0v.x=q0.x+q1.x+q2.x+q3.x; s2v.x=q0.x-q1.x+q2.x-q3.x; av.x=q0.x-q2.x; bv.x=q1.x-q3.x;
    s0v.y=q0.y+q1.y+q2.y+q3.y; s2v.y=q0.y-q1.y+q2.y-q3.y; av.y=q0.y-q2.y; bv.y=q1.y-q3.y;
    s0v.z=q0.z+q1.z+q2.z+q3.z; s2v.z=q0.z-q1.z+q2.z-q3.z; av.z=q0.z-q2.z; bv.z=q1.z-q3.z;
    s0v.w=q0.w+q1.w+q2.w+q3.w; s2v.w=q0.w-q1.w+q2.w-q3.w; av.w=q0.w-q2.w; bv.w=q1.w-q3.w;
    *(float4*)&S0[x][zh*4] = s0v;
    *(float4*)&S2[x][zh*4] = s2v;
    *(float4*)&AB[x][zh*4+0][0] = make_float4(av.x, bv.x, av.y, bv.y);
    *(float4*)&AB[x][zh*4+2][0] = make_float4(av.z, bv.z, av.w, bv.w);
  }
  __syncthreads();

  // ---- analysis: thread = (ks 0..95, xq 0..3); one k, 8 z ----
  {
    const int xq = tid & 3;
    const int ks = tid >> 2;            // 0..95; waves 0-2 even-class, 3-5 odd
    const bool isodd = (ks >= 48);
    const int slot = isodd ? ks - 48 : ks;
    const int ke0 = k0 + (k0 & 1);      // first even >= k0
    const int ko0 = k0 | 1;             // first odd  >= k0
    const int kbase = isodd ? ko0 : ke0;
    const int cnt   = (k1 >= kbase) ? (((k1 - kbase) >> 1) + 1) : 0;
    const bool dual = (cnt > 48);
    int k, x0; bool act;
    if (dual) { k = kbase + 2*(slot + 48*(xq>>1)); x0 = 90*(xq&1); act = (k <= k1); }
    else      { k = kbase + 2*slot;                x0 = 45*xq;     act = (slot < cnt); }

    float ac[8], as[8];
    #pragma unroll
    for (int j=0;j<8;++j){ ac[j]=0.f; as[j]=0.f; }

    if (act) {
      float dc, ds; sincosf((float)k * TH, &ds, &dc);
      float c, s;   sincosf((float)((k * x0) % 720) * TH, &s, &c);
      if (!isodd) {
        const float* Sp = ((((k & 3) == 0) ? &S0[0][0] : &S2[0][0])) + x0*8;
        if (dual) {
          #pragma unroll 5
          for (int i = 0; i < 90; ++i) EVEN_STEP
        } else {
          #pragma unroll 5
          for (int i = 0; i < 45; ++i) EVEN_STEP
        }
      } else {
        const float sg = ((k & 3) == 1) ? 1.0f : -1.0f;
        const float* Ap = &AB[x0][0][0];
        if (dual) {
          #pragma unroll 3
          for (int i = 0; i < 90; ++i) ODD_STEP
        } else {
          #pragma unroll 3
          for (int i = 0; i < 45; ++i) ODD_STEP
        }
      }
    }
    // combine partial sums over the 4-lane xq group
    #pragma unroll
    for (int j=0;j<8;++j){
      ac[j] += __shfl_xor(ac[j], 1);
      as[j] += __shfl_xor(as[j], 1);
    }
    if (!dual) {
      #pragma unroll
      for (int j=0;j<8;++j){
        ac[j] += __shfl_xor(ac[j], 2);
        as[j] += __shfl_xor(as[j], 2);
      }
    }
    if (act && ((xq & (dual ? 1 : 3)) == 0)) {
      const float w = (k==0 || k==360) ? 1.0f : 2.0f;
      const int r = k - k0;
      *(float4*)&SD[r][0][0] = make_float4(w*ac[0], w*as[0], w*ac[1], w*as[1]);
      *(float4*)&SD[r][2][0] = make_float4(w*ac[2], w*as[2], w*ac[3], w*as[3]);
      *(float4*)&SD[r][4][0] = make_float4(w*ac[4], w*as[4], w*ac[5], w*as[5]);
      *(float4*)&SD[r][6][0] = make_float4(w*ac[6], w*as[6], w*ac[7], w*as[7]);
    }
  }
  __syncthreads();

  // ---- synthesis: thread = (x' 0..179, z-half 0..1), 4 z each ----
  if (tid < 360) {
    const int x  = tid % 180;
    const int zh = tid / 180;
    float HreE[2][4]; float Hro[2][4]; float Hio[2][4];
    #pragma unroll
    for (int i = 0; i < 2; ++i)
      #pragma unroll
      for (int j = 0; j < 4; ++j) { HreE[i][j]=0.f; Hro[i][j]=0.f; Hio[i][j]=0.f; }

    const int m4 = (4*x) % 720;
    float dstep_s, dstep_c; sincosf((float)m4 * TH, &dstep_s, &dstep_c);

    // even residues r=0,2: only Re needed
    #pragma unroll
    for (int ri = 0; ri < 2; ++ri) {
      const int r = ri*2;
      const int kst = k0 + ((r - (k0 & 3) + 4) & 3);
      if (kst > k1) continue;
      int mm = (kst * x) % 720;
      float sv, cv; sincosf((float)mm * TH, &sv, &cv);
      #pragma unroll 2
      for (int k = kst; k <= k1; k += 4) {
        const float4 d01 = *(const float4*)&SD[k - k0][zh*4 + 0][0];
        const float4 d23 = *(const float4*)&SD[k - k0][zh*4 + 2][0];
        HreE[ri][0] = fmaf(d01.x, cv, fmaf(d01.y, sv, HreE[ri][0]));
        HreE[ri][1] = fmaf(d01.z, cv, fmaf(d01.w, sv, HreE[ri][1]));
        HreE[ri][2] = fmaf(d23.x, cv, fmaf(d23.y, sv, HreE[ri][2]));
        HreE[ri][3] = fmaf(d23.z, cv, fmaf(d23.w, sv, HreE[ri][3]));
        float nc = fmaf(cv, dstep_c, -sv*dstep_s);   // forward rotation +4x*theta
        float ns = fmaf(sv, dstep_c,  cv*dstep_s);
        cv = nc; sv = ns;
      }
    }
    // odd residues r=1,3: Re and Im
    #pragma unroll
    for (int ri = 0; ri < 2; ++ri) {
      const int r = ri*2 + 1;
      const int kst = k0 + ((r - (k0 & 3) + 4) & 3);
      if (kst > k1) continue;
      int mm = (kst * x) % 720;
      float sv, cv; sincosf((float)mm * TH, &sv, &cv);
      #pragma unroll 2
      for (int k = kst; k <= k1; k += 4) {
        const float4 d01 = *(const float4*)&SD[k - k0][zh*4 + 0][0];
        const float4 d23 = *(const float4*)&SD[k - k0][zh*4 + 2][0];
        Hro[ri][0] = fmaf(d01.x, cv, fmaf(d01.y, sv, Hro[ri][0]));
        Hio[ri][0] = fmaf(d01.y, cv, fmaf(-d01.x, sv, Hio[ri][0]));
        Hro[ri][1] = fmaf(d01.z, cv, fmaf(d01.w, sv, Hro[ri][1]));
        Hio[ri][1] = fmaf(d01.w, cv, fmaf(-d01.z, sv, Hio[ri][1]));
        Hro[ri][2] = fmaf(d23.x, cv, fmaf(d23.y, sv, Hro[ri][2]));
        Hio[ri][2] = fmaf(d23.y, cv, fmaf(-d23.x, sv, Hio[ri][2]));
        Hro[ri][3] = fmaf(d23.z, cv, fmaf(d23.w, sv, Hro[ri][3]));
        Hio[ri][3] = fmaf(d23.w, cv, fmaf(-d23.z, sv, Hio[ri][3]));
        float nc = fmaf(cv, dstep_c, -sv*dstep_s);   // forward rotation +4x*theta
        float ns = fmaf(sv, dstep_c,  cv*dstep_s);
        cv = nc; sv = ns;
      }
    }

    const float inv = 1.0f/720.0f;
    float o[4][4];
    float4 s0v, s2v, ab01, ab23;
    if (!keep) {
      s0v  = *(const float4*)&S0[x][zh*4];
      s2v  = *(const float4*)&S2[x][zh*4];
      ab01 = *(const float4*)&AB[x][zh*4+0][0];
      ab23 = *(const float4*)&AB[x][zh*4+2][0];
    }
    #pragma unroll
    for (int j = 0; j < 4; ++j) {
      const float h0  = HreE[0][j], h2 = HreE[1][j];
      const float h1r = Hro[0][j],  h1i = Hio[0][j];
      const float h3r = Hro[1][j],  h3i = Hio[1][j];
      float l0 = (h0 + h1r + h2 + h3r) * inv;
      float l1 = (h0 + h1i - h2 - h3i) * inv;
      float l2 = (h0 - h1r + h2 - h3r) * inv;
      float l3 = (h0 - h1i - h2 + h3i) * inv;
      if (!keep) {
        const float s0j = (j==0)?s0v.x:(j==1)?s0v.y:(j==2)?s0v.z:s0v.w;
        const float s2j = (j==0)?s2v.x:(j==1)?s2v.y:(j==2)?s2v.z:s2v.w;
        const float aj  = (j==0)?ab01.x:(j==1)?ab01.z:(j==2)?ab23.x:ab23.z;
        const float bj  = (j==0)?ab01.y:(j==1)?ab01.w:(j==2)?ab23.y:ab23.w;
        const float sp = 0.25f*(s0j + s2j), sm = 0.25f*(s0j - s2j);
        const float q0v = sp + 0.5f*aj, q2v = sp - 0.5f*aj;
        const float q1v = sm + 0.5f*bj, q3v = sm - 0.5f*bj;
        l0 = q0v - l0; l1 = q1v - l1; l2 = q2v - l2; l3 = q3v - l3;
      }
      o[0][j] = fminf(fmaxf(l0, -clipv), clipv);
      o[1][j] = fminf(fmaxf(l1, -clipv), clipv);
      o[2][j] = fminf(fmaxf(l2, -clipv), clipv);
      o[3][j] = fminf(fmaxf(l3, -clipv), clipv);
    }
    #pragma unroll
    for (int j = 0; j < 4; ++j) {
      *(float4*)(base + (size_t)(x + 180*j)*NZ + zh*4) =
          make_float4(o[j][0], o[j][1], o[j][2], o[j][3]);
    }
  }
}

// -------------------- host --------------------
extern "C" void kernel_launch(void* const* d_in, const int* in_sizes, int n_in,
                              void* d_out, int out_size, void* d_ws, size_t ws_size,
                              hipStream_t stream) {
  (void)in_sizes; (void)n_in; (void)d_ws; (void)ws_size; (void)out_size;
  const float* u  = (const float*)d_in[0];
  const float* v  = (const float*)d_in[1];
  const float* T  = (const float*)d_in[2];
  const float* ps = (const float*)d_in[4];
  const float* Rp = (const float*)d_in[6];

  float* out = (float*)d_out;
  float* du  = out;
  float* dv  = out + (size_t)NPTS;
  float* dT  = out + (size_t)2*NPTS;
  float* dq  = out + (size_t)3*NPTS;   // staged as div_h scratch; zeroed in filter
  float* dps = out + (size_t)4*NPTS;

  k_divh<<<NPTS/256, 256, 0, stream>>>(u, v, dq);
  k_tend<<<NCOL/8,   256, 0, stream>>>(u, v, T, ps, Rp, dq, du, dv, dT, dps);
  k_filter4b<<<9360, 384, 0, stream>>>(du, dv, dT, dps, dq);
}